// Round 14
// baseline (130.723 us; speedup 1.0000x reference)
//
#include <hip/hip_runtime.h>
#include <math.h>

typedef unsigned int uint;
typedef unsigned short ushort;
typedef __attribute__((ext_vector_type(8))) short short8;
typedef __attribute__((ext_vector_type(4))) float f32x4;

// Problem constants
constexpr int CB  = 8;      // batch B
constexpr int CL  = 2048;   // sequence length L
constexpr int CC  = 256;    // channels NC
constexpr int CHC = 32;     // head channels
constexpr int CGC = 32;     // group channels
constexpr int CHW = 1024;   // H*W (32*32)
constexpr int CNS = 1024;   // n_sample
constexpr int CBG = 64;     // B * n_groups

// Workspace layout (float offsets)
constexpr size_t WS_QCOND = 2176;       // 2048 -> 4224
constexpr size_t WS_WMOD  = 4224;       // bf16 [8][256][256]  -> 266368
constexpr size_t WS_XT    = 266368;     // bf16 [2][1024][256] -> 528512
constexpr size_t WS_QT    = 528512;     // bf16 [8][1024][256] (hw-major) -> 1577088
constexpr size_t WS_XST   = 2756736;    // bf16 [8][1024][256] -> 3805312
constexpr size_t WS_KB    = 3805312;    // bf16 [64][1024][32] -> 4853888
constexpr size_t WS_VB    = 4853888;    // bf16 [64][32][1024] -> 5902464
constexpr size_t WS_WB    = 5902464;    // bf16 Wk,Wv,Wo -> 6000768
constexpr size_t WS_TMPB  = 6000768;    // bf16 [8][2048][256] -> 8097920
constexpr size_t WS_QB    = 8097920;    // bf16 [8][2048][256] -> 10195072
constexpr size_t WS_PART  = 10195072;   // f32 [8][32][256] pooling partials -> 10260608
constexpr size_t WS_MPART = 10260608;   // f32 [8][32] mask partials -> 10260864

static __device__ __forceinline__ ushort f2bf(float f) {
  uint u = __float_as_uint(f);
  return (ushort)((u + 0x7FFFu + ((u >> 16) & 1u)) >> 16);
}
static __device__ __forceinline__ float bf2f(ushort u) {
  return __uint_as_float((uint)u << 16);
}
static __device__ __forceinline__ uint pack2bf(float a, float b) {
  return (uint)f2bf(a) | ((uint)f2bf(b) << 16);
}
// truncating bf16 pack of two floats in one v_perm_b32
static __device__ __forceinline__ uint packtrunc(float lo, float hi) {
  return __builtin_amdgcn_perm(__float_as_uint(hi), __float_as_uint(lo), 0x07060302u);
}

// --- K1: merged — pool partials + q->bf16 | x->x^T bf16 | W->bf16 -----------
__global__ void k_poolprep(const float* __restrict__ q, const float* __restrict__ mask,
                           float* __restrict__ part, float* __restrict__ mpart,
                           ushort* __restrict__ qb,
                           const float* __restrict__ x, const float* __restrict__ Wk,
                           const float* __restrict__ Wv, const float* __restrict__ Wo,
                           ushort* __restrict__ xt, ushort* __restrict__ wb) {
  int bid = blockIdx.x;
  int tid = threadIdx.x;
  __shared__ float shbuf[64 * 65];
  if (bid < 256) {
    int b  = bid >> 5;
    int lc = bid & 31;
    int l0 = lc * 64;
    const float scale = 0.17677669529663687f * 1.4426950408889634f;  // 32^-.5 * log2e
    float* mloc = shbuf;
    if (tid < 64) mloc[tid] = mask[b * CL + l0 + tid];
    __syncthreads();
    if (tid == 0) {
      float s = 0.f;
      for (int j = 0; j < 64; j++) s += mloc[j];
      mpart[b * 32 + lc] = s;
    }
    float acc = 0.f;
    const float* qp = q + (size_t)(b * CL + l0) * CC + tid;
    ushort* qw = qb + (size_t)(b * CL + l0) * CC + tid;
    for (int j = 0; j < 64; j++) {
      float v = qp[(size_t)j * CC];
      acc += v * mloc[j];
      qw[(size_t)j * CC] = f2bf(v * scale);
    }
    part[((size_t)(b * 32 + lc)) * CC + tid] = acc;
  } else if (bid < 384) {
    int b2 = bid - 256;
    int ref  = b2 >> 6;
    int cblk = (b2 >> 4) & 3;
    int hwblk = b2 & 15;
    float (*t)[65] = (float(*)[65])shbuf;
    int c0 = cblk * 64, hw0 = hwblk * 64;
    const float* src = x + (size_t)ref * CC * CHW;
    int hl = tid & 63, cq = tid >> 6;
    #pragma unroll
    for (int r = 0; r < 16; r++) {
      int cl = cq * 16 + r;
      t[cl][hl] = src[(size_t)(c0 + cl) * CHW + hw0 + hl];
    }
    __syncthreads();
    int cl2 = tid & 63, hq = tid >> 6;
    #pragma unroll
    for (int r = 0; r < 16; r++) {
      int hwl = hq * 16 + r;
      xt[((size_t)(ref * CHW + hw0 + hwl)) * CC + c0 + cl2] = f2bf(t[cl2][hwl]);
    }
  } else {
    int t2 = (bid - 384) * 256 + tid;
    int which = t2 >> 13;
    size_t off = ((size_t)(t2 & 8191)) * 8;
    const float* src = (which == 0) ? Wk : (which == 1) ? Wv : Wo;
    float4 a = *(const float4*)(src + off);
    float4 b = *(const float4*)(src + off + 4);
    uint4 r;
    r.x = pack2bf(a.x, a.y); r.y = pack2bf(a.z, a.w);
    r.z = pack2bf(b.x, b.y); r.w = pack2bf(b.z, b.w);
    *(uint4*)(wb + (size_t)which * 65536 + off) = r;
  }
}

// ------- K2: reduce partials -> q_cond = pooled_mean @ Wq.T + bq ------------
__global__ void k_qcond(const float* __restrict__ part, const float* __restrict__ mpart,
                        const float* __restrict__ Wq, const float* __restrict__ bq,
                        float* __restrict__ qcond) {
  int b = blockIdx.x, o = threadIdx.x;
  __shared__ float qm[CC];
  __shared__ float ms;
  float s = 0.f;
  const float* pp = part + (size_t)b * 32 * CC + o;
  #pragma unroll
  for (int lc = 0; lc < 32; lc++) s += pp[(size_t)lc * CC];
  if (o < 32) {
    float m = mpart[b * 32 + o];
    #pragma unroll
    for (int k = 1; k < 32; k <<= 1) m += __shfl_xor(m, k, 32);
    if (o == 0) ms = m;
  }
  __syncthreads();
  float inv = 1.f / (ms + 1e-6f);
  qm[o] = s * inv;
  __syncthreads();
  float acc = bq[o];
  const float* wrow = Wq + (size_t)o * CC;
  for (int i = 0; i < CC; i++) acc += wrow[i] * qm[i];
  qcond[b * CC + o] = acc;
}

// ---------------- K2c: modulated + demodulated weights -> bf16 --------------
__global__ void k_wprep(const float* __restrict__ Wmod, const float* __restrict__ qcond,
                        ushort* __restrict__ wmodb) {
  int b  = blockIdx.x >> 4;
  int og = blockIdx.x & 15;
  int tid = threadIdx.x;
  int ol = tid >> 4, seg = tid & 15;
  int o = og * 16 + ol;
  const float* wr = Wmod + (size_t)o * CC + seg * 16;
  const float* qc = qcond + b * CC + seg * 16;
  float m[16];
  float ss = 0.f;
  #pragma unroll
  for (int j = 0; j < 16; j++) {
    float v = wr[j] * (qc[j] + 1.f);
    m[j] = v;
    ss += v * v;
  }
  #pragma unroll
  for (int k = 1; k < 16; k <<= 1) ss += __shfl_xor(ss, k, 16);
  float d = rsqrtf(ss + 1e-8f);
  uint u[8];
  #pragma unroll
  for (int j = 0; j < 8; j++) u[j] = pack2bf(m[2 * j] * d, m[2 * j + 1] * d);
  ushort* dst = wmodb + ((size_t)(b * CC + o)) * CC + seg * 16;
  *(uint4*)(dst)     = make_uint4(u[0], u[1], u[2], u[3]);
  *(uint4*)(dst + 8) = make_uint4(u[4], u[5], u[6], u[7]);
}

// --- K3: modulated 1x1 conv via MFMA -> qt bf16 hw-major [b][hw][c] ---------
__launch_bounds__(256)
__global__ void k_mod_mfma(const ushort* __restrict__ wmodb, const ushort* __restrict__ xt,
                           ushort* __restrict__ qtb) {
  int tid = threadIdx.x;
  int wid = tid >> 6, lane = tid & 63;
  int widx = blockIdx.x * 4 + wid;
  int b   = widx >> 10;
  int ot  = (widx >> 6) & 15;
  int hwt = widx & 63;
  int col = lane & 15, g = lane >> 4;
  int O0 = ot * 16, HW0 = hwt * 16;
  const ushort* ap = wmodb + ((size_t)(b * CC + O0 + col)) * CC + g * 8;
  const ushort* bp = xt + ((size_t)((b & 1) * CHW + HW0 + col)) * CC + g * 8;
  f32x4 acc = {0.f, 0.f, 0.f, 0.f};
  #pragma unroll
  for (int ks = 0; ks < 8; ks++) {
    short8 af = *(const short8*)(ap + ks * 32);
    short8 bf = *(const short8*)(bp + ks * 32);
    acc = __builtin_amdgcn_mfma_f32_16x16x32_bf16(af, bf, acc, 0, 0, 0);
  }
  uint2 st;
  st.x = pack2bf(acc[0], acc[1]);
  st.y = pack2bf(acc[2], acc[3]);
  *(uint2*)(qtb + ((size_t)(b * CHW + HW0 + col)) * CC + O0 + g * 4) = st;
}

// -- K4: dwconv3x3 + LN + GELU + offset + tanh + ref -> pos -> grid sample ---
__global__ void k_off_sample(const ushort* __restrict__ qtb, const float* __restrict__ dww,
                             const float* __restrict__ dwb, const float* __restrict__ lnw,
                             const float* __restrict__ lnb, const float* __restrict__ offw,
                             const ushort* __restrict__ xt,
                             float* __restrict__ out_pos, float* __restrict__ out_ref,
                             ushort* __restrict__ xst) {
  int bg   = blockIdx.x >> 7;
  int pblk = blockIdx.x & 127;
  int tid  = threadIdx.x;
  int c = tid & 31, pp = tid >> 5;
  int p0 = pblk * 8;
  int yy = p0 >> 5;
  int xx = (p0 & 31) + pp;
  int p  = p0 + pp;
  const ushort* src = qtb + ((size_t)(bg >> 3) * CHW) * CC + (bg & 7) * CGC + c;
  float acc = dwb[c];
  #pragma unroll
  for (int ky = 0; ky < 3; ky++) {
    int yr = yy + ky - 1;
    if (yr < 0 || yr > 31) continue;
    #pragma unroll
    for (int kx = 0; kx < 3; kx++) {
      int xc = xx + kx - 1;
      if (xc < 0 || xc > 31) continue;
      acc += dww[c * 9 + ky * 3 + kx] * bf2f(src[(size_t)(yr * 32 + xc) * CC]);
    }
  }
  float s1 = acc, s2 = acc * acc;
  #pragma unroll
  for (int m = 1; m < 32; m <<= 1) { s1 += __shfl_xor(s1, m, 32); s2 += __shfl_xor(s2, m, 32); }
  float mu  = s1 * (1.f / 32.f);
  float var = s2 * (1.f / 32.f) - mu * mu;
  float tn  = (acc - mu) * rsqrtf(var + 1e-5f) * lnw[c] + lnb[c];
  float g   = 0.5f * tn * (1.f + erff(tn * 0.70710678118654752f));
  float sy = offw[c] * g, sx = offw[32 + c] * g;
  #pragma unroll
  for (int m = 1; m < 32; m <<= 1) { sy += __shfl_xor(sy, m, 32); sx += __shfl_xor(sx, m, 32); }

  float mine  = tanhf((c & 1) ? sx : sy);
  float other = __shfl_xor(mine, 1, 32);
  float ty = (c & 1) ? other : mine;
  float tx = (c & 1) ? mine : other;

  float refy = (0.5f + (float)yy) * (2.f / 31.f) - 1.f;
  float refx = (0.5f + (float)xx) * (2.f / 31.f) - 1.f;
  float py = ty * (2.f / 31.f) + refy;
  float px = tx * (2.f / 31.f) + refx;
  if (c < 2) {
    int oidx = bg * 2048 + p * 2 + c;
    out_pos[oidx] = (c == 0) ? py : px;
    out_ref[oidx] = (c == 0) ? refy : refx;
  }

  float gx = (px + 1.f) * 15.5f;
  float gy = (py + 1.f) * 15.5f;
  float x0f = floorf(gx), y0f = floorf(gy);
  float wx = gx - x0f, wy = gy - y0f;
  int ix0 = (int)x0f, iy0 = (int)y0f;
  const ushort* img = xt + (size_t)(((bg >> 3) & 1)) * CHW * CC + (bg & 7) * CGC + c;
  float sacc = 0.f;
  #pragma unroll
  for (int dy = 0; dy < 2; dy++) {
    int iy = iy0 + dy;
    if (iy < 0 || iy > 31) continue;
    float wyv = dy ? wy : 1.f - wy;
    #pragma unroll
    for (int dx = 0; dx < 2; dx++) {
      int ix = ix0 + dx;
      if (ix < 0 || ix > 31) continue;
      float wxv = dx ? wx : 1.f - wx;
      sacc += wyv * wxv * bf2f(img[(size_t)(iy * 32 + ix) * CC]);
    }
  }
  xst[((size_t)((bg >> 3) * CNS) + p) * CC + (bg & 7) * CGC + c] = f2bf(sacc);
}

// -------- K6: fused K/V projection via MFMA, 2 nt x 2 ot per wave -----------
__launch_bounds__(256)
__global__ void k_kv_mfma(const ushort* __restrict__ xst, const ushort* __restrict__ wkb,
                          const ushort* __restrict__ wvb, const float* __restrict__ bk,
                          const float* __restrict__ bv, ushort* __restrict__ kb,
                          ushort* __restrict__ vb) {
  int tid = threadIdx.x;
  int wid = tid >> 6, lane = tid & 63;
  int widx = blockIdx.x * 4 + wid;       // 2048 waves
  int b   = widx >> 8;                   // 8
  int ntg = (widx >> 3) & 31;            // 32 nt-pairs
  int otg = widx & 7;                    // 8 ot-pairs
  int col = lane & 15, g = lane >> 4;
  int N0 = ntg * 32, O0 = otg * 32;

  const ushort* xs0 = xst + ((size_t)(b * CNS + N0 + col)) * CC + g * 8;
  const ushort* xs1 = xs0 + (size_t)16 * CC;
  const ushort* wk0 = wkb + (size_t)(O0 + col) * CC + g * 8;
  const ushort* wk1 = wk0 + (size_t)16 * CC;
  const ushort* wv0 = wvb + (size_t)(O0 + col) * CC + g * 8;
  const ushort* wv1 = wv0 + (size_t)16 * CC;

  f32x4 ka[2][2], va[2][2];
  #pragma unroll
  for (int Y = 0; Y < 2; Y++) {
    float bvv = bv[O0 + Y * 16 + col];
    #pragma unroll
    for (int r = 0; r < 4; r++) {
      float bkv = bk[O0 + Y * 16 + g * 4 + r];
      ka[0][Y][r] = bkv; ka[1][Y][r] = bkv;
      va[0][Y][r] = bvv; va[1][Y][r] = bvv;
    }
  }

  #pragma unroll
  for (int ks = 0; ks < 8; ks++) {
    short8 xf0 = *(const short8*)(xs0 + ks * 32);
    short8 xf1 = *(const short8*)(xs1 + ks * 32);
    short8 kf0 = *(const short8*)(wk0 + ks * 32);
    short8 kf1 = *(const short8*)(wk1 + ks * 32);
    short8 vf0 = *(const short8*)(wv0 + ks * 32);
    short8 vf1 = *(const short8*)(wv1 + ks * 32);
    ka[0][0] = __builtin_amdgcn_mfma_f32_16x16x32_bf16(kf0, xf0, ka[0][0], 0, 0, 0);
    ka[0][1] = __builtin_amdgcn_mfma_f32_16x16x32_bf16(kf1, xf0, ka[0][1], 0, 0, 0);
    ka[1][0] = __builtin_amdgcn_mfma_f32_16x16x32_bf16(kf0, xf1, ka[1][0], 0, 0, 0);
    ka[1][1] = __builtin_amdgcn_mfma_f32_16x16x32_bf16(kf1, xf1, ka[1][1], 0, 0, 0);
    va[0][0] = __builtin_amdgcn_mfma_f32_16x16x32_bf16(xf0, vf0, va[0][0], 0, 0, 0);
    va[0][1] = __builtin_amdgcn_mfma_f32_16x16x32_bf16(xf0, vf1, va[0][1], 0, 0, 0);
    va[1][0] = __builtin_amdgcn_mfma_f32_16x16x32_bf16(xf1, vf0, va[1][0], 0, 0, 0);
    va[1][1] = __builtin_amdgcn_mfma_f32_16x16x32_bf16(xf1, vf1, va[1][1], 0, 0, 0);
  }

  #pragma unroll
  for (int X = 0; X < 2; X++)
    #pragma unroll
    for (int Y = 0; Y < 2; Y++) {
      int Oy = O0 + Y * 16, Nx = N0 + X * 16;
      {
        int hh = Oy >> 5;
        int c0 = (Oy & 31) + g * 4;
        uint2 w;
        w.x = pack2bf(ka[X][Y][0], ka[X][Y][1]);
        w.y = pack2bf(ka[X][Y][2], ka[X][Y][3]);
        *(uint2*)(kb + ((size_t)((b * 8 + hh) * CNS + Nx + col)) * CHC + c0) = w;
      }
      {
        int o = Oy + col;
        int hh = o >> 5;
        uint2 w;
        w.x = pack2bf(va[X][Y][0], va[X][Y][1]);
        w.y = pack2bf(va[X][Y][2], va[X][Y][3]);
        *(uint2*)(vb + ((size_t)((b * 8 + hh) * CHC + (o & 31))) * CNS + Nx + g * 4) = w;
      }
    }
}

// -------- K7: MFMA flash attention, 64 q per wave (4 tiles) ------------------
// 256 blocks (1/CU), 8 waves x 64 q. K/V fragment LDS reads amortized over
// 4 q-tiles (halved vs 32q/wave). 2-chunk slots, dual-buffered staging,
// 4 per-wave P buffers. 16B-aligned pads (K 80B rows, V 144B rows).
__launch_bounds__(512, 2)
__global__ void k_attn_mfma(const ushort* __restrict__ qb, const ushort* __restrict__ kb,
                            const ushort* __restrict__ vb, ushort* __restrict__ tmpb) {
  int bh = blockIdx.x >> 2;          // 64
  int mb = blockIdx.x & 3;           // 4 m-blocks of 512 rows
  int b = bh >> 3, h = bh & 7;
  int tid = threadIdx.x;
  int wid = tid >> 6, lane = tid & 63;
  int col = lane & 15, g = lane >> 4;
  int mQ = mb * 512 + wid * 64;      // wave's q base; tiles at +0,+16,+32,+48

  __shared__ ushort Kst[2][2][64 * 40];  // [buf][slot] 80B rows
  __shared__ ushort Vst[2][2][32 * 72];  // [buf][slot] 144B rows
  __shared__ ushort plds[8][4][1024];    // 4 P buffers per wave (2KB each)

  char* pw = (char*)&plds[wid][0][0];
  int swz = (col & 7) << 4;
  int wb0 = col * 128 + g * 8;
  int rb0 = (col * 128 + g * 16) ^ swz;
  int rb1 = (col * 128 + 64 + g * 16) ^ swz;

  short8 qf[4];
  #pragma unroll
  for (int t = 0; t < 4; t++)
    qf[t] = *(const short8*)(qb + ((size_t)(b * CL + mQ + t * 16 + col)) * CC + h * CHC + g * 8);

  const ushort* kglob = kb + (size_t)bh * 32768 + tid * 4;            // [n][c]
  const ushort* vglob = vb + (size_t)bh * 32768 + (tid >> 4) * 1024 + (tid & 15) * 4;  // [c][n]
  int kdst = (tid >> 3) * 40 + (tid & 7) * 4;
  int vdst = (tid >> 4) * 72 + (tid & 15) * 4;

  f32x4 oacc[4][2];
  #pragma unroll
  for (int t = 0; t < 4; t++) {
    oacc[t][0] = (f32x4){0.f, 0.f, 0.f, 0.f};
    oacc[t][1] = (f32x4){0.f, 0.f, 0.f, 0.f};
  }
  float lsum[4] = {0.f, 0.f, 0.f, 0.f};

  // prologue: stage chunks 0,1 into buf 0
  {
    uint2 k0 = *(const uint2*)(kglob);
    uint2 k1 = *(const uint2*)(kglob + 2048);
    uint2 v0 = *(const uint2*)(vglob);
    uint2 v1 = *(const uint2*)(vglob + 64);
    *(uint2*)&Kst[0][0][kdst] = k0;
    *(uint2*)&Kst[0][1][kdst] = k1;
    *(uint2*)&Vst[0][0][vdst] = v0;
    *(uint2*)&Vst[0][1][vdst] = v1;
  }
  __syncthreads();

  int cur = 0;
  for (int it = 0; it < 8; it++) {
    uint2 kx0, kx1, vx0, vx1;
    if (it < 7) {
      int cb = (it + 1) * 2;
      kx0 = *(const uint2*)(kglob + (size_t)cb * 2048);
      kx1 = *(const uint2*)(kglob + (size_t)(cb + 1) * 2048);
      vx0 = *(const uint2*)(vglob + (size_t)cb * 64);
      vx1 = *(const uint2*)(vglob + (size_t)(cb + 1) * 64);
    }

    #pragma unroll
    for (int s = 0; s < 2; s++) {
      const ushort* Kc = &Kst[cur][s][0];
      const ushort* Vc = &Vst[cur][s][0];
      short8 kf0 = *(const short8*)(Kc + ( 0 + col) * 40 + g * 8);
      short8 kf1 = *(const short8*)(Kc + (16 + col) * 40 + g * 8);
      short8 kf2 = *(const short8*)(Kc + (32 + col) * 40 + g * 8);
      short8 kf3 = *(const short8*)(Kc + (48 + col) * 40 + g * 8);
      short8 vf00 = *(const short8*)(Vc + (col     ) * 72 +  0 + g * 8);
      short8 vf01 = *(const short8*)(Vc + (col     ) * 72 + 32 + g * 8);
      short8 vf10 = *(const short8*)(Vc + (col + 16) * 72 +  0 + g * 8);
      short8 vf11 = *(const short8*)(Vc + (col + 16) * 72 + 32 + g * 8);

      f32x4 zero = {0.f, 0.f, 0.f, 0.f};
      #pragma unroll
      for (int t = 0; t < 4; t++) {
        char* pwt = pw + t * 2048;
        f32x4 s0 = __builtin_amdgcn_mfma_f32_16x16x32_bf16(kf0, qf[t], zero, 0, 0, 0);
        f32x4 s1 = __builtin_amdgcn_mfma_f32_16x16x32_bf16(kf1, qf[t], zero, 0, 0, 0);
        f32x4 s2 = __builtin_amdgcn_mfma_f32_16x16x32_bf16(kf2, qf[t], zero, 0, 0, 0);
        f32x4 s3 = __builtin_amdgcn_mfma_f32_16x16x32_bf16(kf3, qf[t], zero, 0, 0, 0);
        float ps = 0.f;
        #pragma unroll
        for (int f = 0; f < 4; f++) {
          f32x4 sv = (f == 0) ? s0 : (f == 1) ? s1 : (f == 2) ? s2 : s3;
          float p0 = __builtin_amdgcn_exp2f(sv[0]);
          float p1 = __builtin_amdgcn_exp2f(sv[1]);
          float p2 = __builtin_amdgcn_exp2f(sv[2]);
          float p3 = __builtin_amdgcn_exp2f(sv[3]);
          ps += (p0 + p1) + (p2 + p3);
          *(uint2*)(pwt + ((wb0 + f * 32) ^ swz)) = make_uint2(packtrunc(p0, p1), packtrunc(p2, p3));
        }
        lsum[t] += ps;
        short8 pf0 = *(const short8*)(pwt + rb0);
        short8 pf1 = *(const short8*)(pwt + rb1);
        oacc[t][0] = __builtin_amdgcn_mfma_f32_16x16x32_bf16(vf00, pf0, oacc[t][0], 0, 0, 0);
        oacc[t][0] = __builtin_amdgcn_mfma_f32_16x16x32_bf16(vf01, pf1, oacc[t][0], 0, 0, 0);
        oacc[t][1] = __builtin_amdgcn_mfma_f32_16x16x32_bf16(vf10, pf0, oacc[t][1], 0, 0, 0);
        oacc[t][1] = __builtin_amdgcn_mfma_f32_16x16x32_bf16(vf11, pf1, oacc[t][1], 0, 0, 0);
      }
    }

    if (it < 7) {
      *(uint2*)&Kst[cur ^ 1][0][kdst] = kx0;
      *(uint2*)&Kst[cur ^ 1][1][kdst] = kx1;
      *(uint2*)&Vst[cur ^ 1][0][vdst] = vx0;
      *(uint2*)&Vst[cur ^ 1][1][vdst] = vx1;
    }
    __syncthreads();
    cur ^= 1;
  }

  #pragma unroll
  for (int t = 0; t < 4; t++) {
    float l = lsum[t];
    l += __shfl_xor(l, 16);
    l += __shfl_xor(l, 32);
    float rl = 1.f / l;
    ushort* op = tmpb + ((size_t)(b * CL + mQ + t * 16 + col)) * CC + h * CHC;
    uint2 w0, w1;
    w0.x = pack2bf(oacc[t][0][0] * rl, oacc[t][0][1] * rl);
    w0.y = pack2bf(oacc[t][0][2] * rl, oacc[t][0][3] * rl);
    w1.x = pack2bf(oacc[t][1][0] * rl, oacc[t][1][1] * rl);
    w1.y = pack2bf(oacc[t][1][2] * rl, oacc[t][1][3] * rl);
    *(uint2*)(op + g * 4) = w0;
    *(uint2*)(op + 16 + g * 4) = w1;
  }
}

// ------- K8: y = tmp_bf @ Wo_bf^T + bo via MFMA (2 r-tiles x 8 o-tiles) -----
__launch_bounds__(256)
__global__ void k_yproj_mfma(const ushort* __restrict__ tmpb, const ushort* __restrict__ wob,
                             const float* __restrict__ bo, float* __restrict__ y) {
  int tid = threadIdx.x;
  int wid = tid >> 6, lane = tid & 63;
  int widx = blockIdx.x * 4 + wid;      // 1024 waves
  int rt2 = widx >> 1;                  // 512 row-pairs
  int og = widx & 1;                    // 2 o-groups of 128
  int col = lane & 15, g = lane >> 4;
  int R0 = rt2 * 32, O0 = og * 128;

  const ushort* ap0 = tmpb + ((size_t)(R0 + col)) * CC + g * 8;
  const ushort* ap1 = ap0 + (size_t)16 * CC;
  const ushort* bp = wob + (size_t)(O0 + col) * CC + g * 8;

  f32x4 acc[2][8];
  #pragma unroll
  for (int o4 = 0; o4 < 8; o4++) {
    float bb = bo[O0 + o4 * 16 + col];
    #pragma unroll
    for (int r = 0; r < 4; r++) { acc[0][o4][r] = bb; acc[1][o4][r] = bb; }
  }

  #pragma unroll
  for (int ks = 0; ks < 8; ks++) {
    short8 af0 = *(const short8*)(ap0 + ks * 32);
    short8 af1 = *(const short8*)(ap1 + ks * 32);
    #pragma unroll
    for (int o4 = 0; o4 < 8; o4++) {
      short8 bf = *(const short8*)(bp + (size_t)o4 * 16 * CC + ks * 32);
      acc[0][o4] = __builtin_amdgcn_mfma_f32_16x16x32_bf16(af0, bf, acc[0][o4], 0, 0, 0);
      acc[1][o4] = __builtin_amdgcn_mfma_f32_16x16x32_bf16(af1, bf, acc[1][o4], 0, 0, 0);
    }
  }

  #pragma unroll
  for (int rr = 0; rr < 2; rr++)
    #pragma unroll
    for (int o4 = 0; o4 < 8; o4++)
      #pragma unroll
      for (int r = 0; r < 4; r++)
        y[(size_t)(R0 + rr * 16 + g * 4 + r) * CC + O0 + o4 * 16 + col] = acc[rr][o4][r];
}

extern "C" void kernel_launch(void* const* d_in, const int* in_sizes, int n_in,
                              void* d_out, int out_size, void* d_ws, size_t ws_size,
                              hipStream_t stream) {
  const float* x    = (const float*)d_in[0];
  const float* q    = (const float*)d_in[1];
  const float* mask = (const float*)d_in[2];
  const float* Wq   = (const float*)d_in[3];
  const float* bq   = (const float*)d_in[4];
  const float* Wmod = (const float*)d_in[5];
  const float* dw_w = (const float*)d_in[6];
  const float* dw_b = (const float*)d_in[7];
  const float* ln_w = (const float*)d_in[8];
  const float* ln_b = (const float*)d_in[9];
  const float* offw = (const float*)d_in[10];
  const float* Wk   = (const float*)d_in[11];
  const float* bk   = (const float*)d_in[12];
  const float* Wv   = (const float*)d_in[13];
  const float* bv   = (const float*)d_in[14];
  const float* Wo   = (const float*)d_in[15];
  const float* bo   = (const float*)d_in[16];

  float* ws = (float*)d_ws;
  float* out = (float*)d_out;
  float* out_y   = out;
  float* out_pos = out + (size_t)CB * CL * CC;
  float* out_ref = out_pos + (size_t)CBG * CHW * 2;

  ushort* wmodb = (ushort*)(ws + WS_WMOD);
  ushort* xt    = (ushort*)(ws + WS_XT);
  ushort* qtb   = (ushort*)(ws + WS_QT);
  ushort* xst   = (ushort*)(ws + WS_XST);
  ushort* kbuf  = (ushort*)(ws + WS_KB);
  ushort* vbuf  = (ushort*)(ws + WS_VB);
  ushort* wkb   = (ushort*)(ws + WS_WB);
  ushort* wvb   = wkb + 65536;
  ushort* wob   = wkb + 131072;
  ushort* tmpb  = (ushort*)(ws + WS_TMPB);
  ushort* qbuf  = (ushort*)(ws + WS_QB);
  float*  part  = ws + WS_PART;
  float*  mpart = ws + WS_MPART;

  k_poolprep<<<480, 256, 0, stream>>>(q, mask, part, mpart, qbuf, x, Wk, Wv, Wo, xt, wkb);
  k_qcond<<<8, 256, 0, stream>>>(part, mpart, Wq, bq, ws + WS_QCOND);
  k_wprep<<<128, 256, 0, stream>>>(Wmod, ws + WS_QCOND, wmodb);
  k_mod_mfma<<<2048, 256, 0, stream>>>(wmodb, xt, qtb);
  k_off_sample<<<8192, 256, 0, stream>>>(qtb, dw_w, dw_b, ln_w, ln_b, offw, xt,
                                         out_pos, out_ref, xst);
  k_kv_mfma<<<512, 256, 0, stream>>>(xst, wkb, wvb, bk, bv, kbuf, vbuf);
  k_attn_mfma<<<256, 512, 0, stream>>>(qbuf, kbuf, vbuf, tmpb);
  k_yproj_mfma<<<256, 256, 0, stream>>>(tmpb, wob, bo, out_y);
}

// Round 15
// 126.573 us; speedup vs baseline: 1.0328x; 1.0328x over previous
//
#include <hip/hip_runtime.h>
#include <math.h>

typedef unsigned int uint;
typedef unsigned short ushort;
typedef __attribute__((ext_vector_type(8))) short short8;
typedef __attribute__((ext_vector_type(4))) float f32x4;

// Problem constants
constexpr int CB  = 8;      // batch B
constexpr int CL  = 2048;   // sequence length L
constexpr int CC  = 256;    // channels NC
constexpr int CHC = 32;     // head channels
constexpr int CGC = 32;     // group channels
constexpr int CHW = 1024;   // H*W (32*32)
constexpr int CNS = 1024;   // n_sample
constexpr int CBG = 64;     // B * n_groups

// Workspace layout (float offsets)
constexpr size_t WS_QCOND = 2176;       // 2048 -> 4224
constexpr size_t WS_WMOD  = 4224;       // bf16 [8][256][256]  -> 266368
constexpr size_t WS_XT    = 266368;     // bf16 [2][1024][256] -> 528512
constexpr size_t WS_QT    = 528512;     // bf16 [8][1024][256] (hw-major) -> 1577088
constexpr size_t WS_XST   = 2756736;    // bf16 [8][1024][256] -> 3805312
constexpr size_t WS_KB    = 3805312;    // bf16 [64][1024][32] -> 4853888
constexpr size_t WS_VB    = 4853888;    // bf16 [64][32][1024] -> 5902464
constexpr size_t WS_WB    = 5902464;    // bf16 Wk,Wv,Wo -> 6000768
constexpr size_t WS_TMPB  = 6000768;    // bf16 [8][2048][256] -> 8097920
constexpr size_t WS_QB    = 8097920;    // bf16 [8][2048][256] -> 10195072
constexpr size_t WS_PART  = 10195072;   // f32 [8][32][256] pooling partials -> 10260608
constexpr size_t WS_MPART = 10260608;   // f32 [8][32] mask partials -> 10260864

static __device__ __forceinline__ ushort f2bf(float f) {
  uint u = __float_as_uint(f);
  return (ushort)((u + 0x7FFFu + ((u >> 16) & 1u)) >> 16);
}
static __device__ __forceinline__ float bf2f(ushort u) {
  return __uint_as_float((uint)u << 16);
}
static __device__ __forceinline__ uint pack2bf(float a, float b) {
  return (uint)f2bf(a) | ((uint)f2bf(b) << 16);
}
// truncating bf16 pack of two floats in one v_perm_b32
static __device__ __forceinline__ uint packtrunc(float lo, float hi) {
  return __builtin_amdgcn_perm(__float_as_uint(hi), __float_as_uint(lo), 0x07060302u);
}

// --- K1: merged — pool partials + q->bf16 | x->x^T bf16 | W->bf16 -----------
__global__ void k_poolprep(const float* __restrict__ q, const float* __restrict__ mask,
                           float* __restrict__ part, float* __restrict__ mpart,
                           ushort* __restrict__ qb,
                           const float* __restrict__ x, const float* __restrict__ Wk,
                           const float* __restrict__ Wv, const float* __restrict__ Wo,
                           ushort* __restrict__ xt, ushort* __restrict__ wb) {
  int bid = blockIdx.x;
  int tid = threadIdx.x;
  __shared__ float shbuf[64 * 65];
  if (bid < 256) {
    int b  = bid >> 5;
    int lc = bid & 31;
    int l0 = lc * 64;
    const float scale = 0.17677669529663687f * 1.4426950408889634f;  // 32^-.5 * log2e
    float* mloc = shbuf;
    if (tid < 64) mloc[tid] = mask[b * CL + l0 + tid];
    __syncthreads();
    if (tid == 0) {
      float s = 0.f;
      for (int j = 0; j < 64; j++) s += mloc[j];
      mpart[b * 32 + lc] = s;
    }
    float acc = 0.f;
    const float* qp = q + (size_t)(b * CL + l0) * CC + tid;
    ushort* qw = qb + (size_t)(b * CL + l0) * CC + tid;
    for (int j = 0; j < 64; j++) {
      float v = qp[(size_t)j * CC];
      acc += v * mloc[j];
      qw[(size_t)j * CC] = f2bf(v * scale);
    }
    part[((size_t)(b * 32 + lc)) * CC + tid] = acc;
  } else if (bid < 384) {
    int b2 = bid - 256;
    int ref  = b2 >> 6;
    int cblk = (b2 >> 4) & 3;
    int hwblk = b2 & 15;
    float (*t)[65] = (float(*)[65])shbuf;
    int c0 = cblk * 64, hw0 = hwblk * 64;
    const float* src = x + (size_t)ref * CC * CHW;
    int hl = tid & 63, cq = tid >> 6;
    #pragma unroll
    for (int r = 0; r < 16; r++) {
      int cl = cq * 16 + r;
      t[cl][hl] = src[(size_t)(c0 + cl) * CHW + hw0 + hl];
    }
    __syncthreads();
    int cl2 = tid & 63, hq = tid >> 6;
    #pragma unroll
    for (int r = 0; r < 16; r++) {
      int hwl = hq * 16 + r;
      xt[((size_t)(ref * CHW + hw0 + hwl)) * CC + c0 + cl2] = f2bf(t[cl2][hwl]);
    }
  } else {
    int t2 = (bid - 384) * 256 + tid;
    int which = t2 >> 13;
    size_t off = ((size_t)(t2 & 8191)) * 8;
    const float* src = (which == 0) ? Wk : (which == 1) ? Wv : Wo;
    float4 a = *(const float4*)(src + off);
    float4 b = *(const float4*)(src + off + 4);
    uint4 r;
    r.x = pack2bf(a.x, a.y); r.y = pack2bf(a.z, a.w);
    r.z = pack2bf(b.x, b.y); r.w = pack2bf(b.z, b.w);
    *(uint4*)(wb + (size_t)which * 65536 + off) = r;
  }
}

// ------- K2: reduce partials -> q_cond = pooled_mean @ Wq.T + bq ------------
__global__ void k_qcond(const float* __restrict__ part, const float* __restrict__ mpart,
                        const float* __restrict__ Wq, const float* __restrict__ bq,
                        float* __restrict__ qcond) {
  int b = blockIdx.x, o = threadIdx.x;
  __shared__ float qm[CC];
  __shared__ float ms;
  float s = 0.f;
  const float* pp = part + (size_t)b * 32 * CC + o;
  #pragma unroll
  for (int lc = 0; lc < 32; lc++) s += pp[(size_t)lc * CC];
  if (o < 32) {
    float m = mpart[b * 32 + o];
    #pragma unroll
    for (int k = 1; k < 32; k <<= 1) m += __shfl_xor(m, k, 32);
    if (o == 0) ms = m;
  }
  __syncthreads();
  float inv = 1.f / (ms + 1e-6f);
  qm[o] = s * inv;
  __syncthreads();
  float acc = bq[o];
  const float* wrow = Wq + (size_t)o * CC;
  for (int i = 0; i < CC; i++) acc += wrow[i] * qm[i];
  qcond[b * CC + o] = acc;
}

// ---------------- K2c: modulated + demodulated weights -> bf16 --------------
__global__ void k_wprep(const float* __restrict__ Wmod, const float* __restrict__ qcond,
                        ushort* __restrict__ wmodb) {
  int b  = blockIdx.x >> 4;
  int og = blockIdx.x & 15;
  int tid = threadIdx.x;
  int ol = tid >> 4, seg = tid & 15;
  int o = og * 16 + ol;
  const float* wr = Wmod + (size_t)o * CC + seg * 16;
  const float* qc = qcond + b * CC + seg * 16;
  float m[16];
  float ss = 0.f;
  #pragma unroll
  for (int j = 0; j < 16; j++) {
    float v = wr[j] * (qc[j] + 1.f);
    m[j] = v;
    ss += v * v;
  }
  #pragma unroll
  for (int k = 1; k < 16; k <<= 1) ss += __shfl_xor(ss, k, 16);
  float d = rsqrtf(ss + 1e-8f);
  uint u[8];
  #pragma unroll
  for (int j = 0; j < 8; j++) u[j] = pack2bf(m[2 * j] * d, m[2 * j + 1] * d);
  ushort* dst = wmodb + ((size_t)(b * CC + o)) * CC + seg * 16;
  *(uint4*)(dst)     = make_uint4(u[0], u[1], u[2], u[3]);
  *(uint4*)(dst + 8) = make_uint4(u[4], u[5], u[6], u[7]);
}

// --- K3: modulated 1x1 conv via MFMA -> qt bf16 hw-major [b][hw][c] ---------
__launch_bounds__(256)
__global__ void k_mod_mfma(const ushort* __restrict__ wmodb, const ushort* __restrict__ xt,
                           ushort* __restrict__ qtb) {
  int tid = threadIdx.x;
  int wid = tid >> 6, lane = tid & 63;
  int widx = blockIdx.x * 4 + wid;
  int b   = widx >> 10;
  int ot  = (widx >> 6) & 15;
  int hwt = widx & 63;
  int col = lane & 15, g = lane >> 4;
  int O0 = ot * 16, HW0 = hwt * 16;
  const ushort* ap = wmodb + ((size_t)(b * CC + O0 + col)) * CC + g * 8;
  const ushort* bp = xt + ((size_t)((b & 1) * CHW + HW0 + col)) * CC + g * 8;
  f32x4 acc = {0.f, 0.f, 0.f, 0.f};
  #pragma unroll
  for (int ks = 0; ks < 8; ks++) {
    short8 af = *(const short8*)(ap + ks * 32);
    short8 bf = *(const short8*)(bp + ks * 32);
    acc = __builtin_amdgcn_mfma_f32_16x16x32_bf16(af, bf, acc, 0, 0, 0);
  }
  uint2 st;
  st.x = pack2bf(acc[0], acc[1]);
  st.y = pack2bf(acc[2], acc[3]);
  *(uint2*)(qtb + ((size_t)(b * CHW + HW0 + col)) * CC + O0 + g * 4) = st;
}

// -- K4: dwconv3x3 + LN + GELU + offset + tanh + ref -> pos -> grid sample ---
__global__ void k_off_sample(const ushort* __restrict__ qtb, const float* __restrict__ dww,
                             const float* __restrict__ dwb, const float* __restrict__ lnw,
                             const float* __restrict__ lnb, const float* __restrict__ offw,
                             const ushort* __restrict__ xt,
                             float* __restrict__ out_pos, float* __restrict__ out_ref,
                             ushort* __restrict__ xst) {
  int bg   = blockIdx.x >> 7;
  int pblk = blockIdx.x & 127;
  int tid  = threadIdx.x;
  int c = tid & 31, pp = tid >> 5;
  int p0 = pblk * 8;
  int yy = p0 >> 5;
  int xx = (p0 & 31) + pp;
  int p  = p0 + pp;
  const ushort* src = qtb + ((size_t)(bg >> 3) * CHW) * CC + (bg & 7) * CGC + c;
  float acc = dwb[c];
  #pragma unroll
  for (int ky = 0; ky < 3; ky++) {
    int yr = yy + ky - 1;
    if (yr < 0 || yr > 31) continue;
    #pragma unroll
    for (int kx = 0; kx < 3; kx++) {
      int xc = xx + kx - 1;
      if (xc < 0 || xc > 31) continue;
      acc += dww[c * 9 + ky * 3 + kx] * bf2f(src[(size_t)(yr * 32 + xc) * CC]);
    }
  }
  float s1 = acc, s2 = acc * acc;
  #pragma unroll
  for (int m = 1; m < 32; m <<= 1) { s1 += __shfl_xor(s1, m, 32); s2 += __shfl_xor(s2, m, 32); }
  float mu  = s1 * (1.f / 32.f);
  float var = s2 * (1.f / 32.f) - mu * mu;
  float tn  = (acc - mu) * rsqrtf(var + 1e-5f) * lnw[c] + lnb[c];
  float g   = 0.5f * tn * (1.f + erff(tn * 0.70710678118654752f));
  float sy = offw[c] * g, sx = offw[32 + c] * g;
  #pragma unroll
  for (int m = 1; m < 32; m <<= 1) { sy += __shfl_xor(sy, m, 32); sx += __shfl_xor(sx, m, 32); }

  float mine  = tanhf((c & 1) ? sx : sy);
  float other = __shfl_xor(mine, 1, 32);
  float ty = (c & 1) ? other : mine;
  float tx = (c & 1) ? mine : other;

  float refy = (0.5f + (float)yy) * (2.f / 31.f) - 1.f;
  float refx = (0.5f + (float)xx) * (2.f / 31.f) - 1.f;
  float py = ty * (2.f / 31.f) + refy;
  float px = tx * (2.f / 31.f) + refx;
  if (c < 2) {
    int oidx = bg * 2048 + p * 2 + c;
    out_pos[oidx] = (c == 0) ? py : px;
    out_ref[oidx] = (c == 0) ? refy : refx;
  }

  float gx = (px + 1.f) * 15.5f;
  float gy = (py + 1.f) * 15.5f;
  float x0f = floorf(gx), y0f = floorf(gy);
  float wx = gx - x0f, wy = gy - y0f;
  int ix0 = (int)x0f, iy0 = (int)y0f;
  const ushort* img = xt + (size_t)(((bg >> 3) & 1)) * CHW * CC + (bg & 7) * CGC + c;
  float sacc = 0.f;
  #pragma unroll
  for (int dy = 0; dy < 2; dy++) {
    int iy = iy0 + dy;
    if (iy < 0 || iy > 31) continue;
    float wyv = dy ? wy : 1.f - wy;
    #pragma unroll
    for (int dx = 0; dx < 2; dx++) {
      int ix = ix0 + dx;
      if (ix < 0 || ix > 31) continue;
      float wxv = dx ? wx : 1.f - wx;
      sacc += wyv * wxv * bf2f(img[(size_t)(iy * 32 + ix) * CC]);
    }
  }
  xst[((size_t)((bg >> 3) * CNS) + p) * CC + (bg & 7) * CGC + c] = f2bf(sacc);
}

// -------- K6: fused K/V projection via MFMA, 2 nt x 2 ot per wave -----------
__launch_bounds__(256)
__global__ void k_kv_mfma(const ushort* __restrict__ xst, const ushort* __restrict__ wkb,
                          const ushort* __restrict__ wvb, const float* __restrict__ bk,
                          const float* __restrict__ bv, ushort* __restrict__ kb,
                          ushort* __restrict__ vb) {
  int tid = threadIdx.x;
  int wid = tid >> 6, lane = tid & 63;
  int widx = blockIdx.x * 4 + wid;       // 2048 waves
  int b   = widx >> 8;                   // 8
  int ntg = (widx >> 3) & 31;            // 32 nt-pairs
  int otg = widx & 7;                    // 8 ot-pairs
  int col = lane & 15, g = lane >> 4;
  int N0 = ntg * 32, O0 = otg * 32;

  const ushort* xs0 = xst + ((size_t)(b * CNS + N0 + col)) * CC + g * 8;
  const ushort* xs1 = xs0 + (size_t)16 * CC;
  const ushort* wk0 = wkb + (size_t)(O0 + col) * CC + g * 8;
  const ushort* wk1 = wk0 + (size_t)16 * CC;
  const ushort* wv0 = wvb + (size_t)(O0 + col) * CC + g * 8;
  const ushort* wv1 = wv0 + (size_t)16 * CC;

  f32x4 ka[2][2], va[2][2];
  #pragma unroll
  for (int Y = 0; Y < 2; Y++) {
    float bvv = bv[O0 + Y * 16 + col];
    #pragma unroll
    for (int r = 0; r < 4; r++) {
      float bkv = bk[O0 + Y * 16 + g * 4 + r];
      ka[0][Y][r] = bkv; ka[1][Y][r] = bkv;
      va[0][Y][r] = bvv; va[1][Y][r] = bvv;
    }
  }

  #pragma unroll
  for (int ks = 0; ks < 8; ks++) {
    short8 xf0 = *(const short8*)(xs0 + ks * 32);
    short8 xf1 = *(const short8*)(xs1 + ks * 32);
    short8 kf0 = *(const short8*)(wk0 + ks * 32);
    short8 kf1 = *(const short8*)(wk1 + ks * 32);
    short8 vf0 = *(const short8*)(wv0 + ks * 32);
    short8 vf1 = *(const short8*)(wv1 + ks * 32);
    ka[0][0] = __builtin_amdgcn_mfma_f32_16x16x32_bf16(kf0, xf0, ka[0][0], 0, 0, 0);
    ka[0][1] = __builtin_amdgcn_mfma_f32_16x16x32_bf16(kf1, xf0, ka[0][1], 0, 0, 0);
    ka[1][0] = __builtin_amdgcn_mfma_f32_16x16x32_bf16(kf0, xf1, ka[1][0], 0, 0, 0);
    ka[1][1] = __builtin_amdgcn_mfma_f32_16x16x32_bf16(kf1, xf1, ka[1][1], 0, 0, 0);
    va[0][0] = __builtin_amdgcn_mfma_f32_16x16x32_bf16(xf0, vf0, va[0][0], 0, 0, 0);
    va[0][1] = __builtin_amdgcn_mfma_f32_16x16x32_bf16(xf0, vf1, va[0][1], 0, 0, 0);
    va[1][0] = __builtin_amdgcn_mfma_f32_16x16x32_bf16(xf1, vf0, va[1][0], 0, 0, 0);
    va[1][1] = __builtin_amdgcn_mfma_f32_16x16x32_bf16(xf1, vf1, va[1][1], 0, 0, 0);
  }

  #pragma unroll
  for (int X = 0; X < 2; X++)
    #pragma unroll
    for (int Y = 0; Y < 2; Y++) {
      int Oy = O0 + Y * 16, Nx = N0 + X * 16;
      {
        int hh = Oy >> 5;
        int c0 = (Oy & 31) + g * 4;
        uint2 w;
        w.x = pack2bf(ka[X][Y][0], ka[X][Y][1]);
        w.y = pack2bf(ka[X][Y][2], ka[X][Y][3]);
        *(uint2*)(kb + ((size_t)((b * 8 + hh) * CNS + Nx + col)) * CHC + c0) = w;
      }
      {
        int o = Oy + col;
        int hh = o >> 5;
        uint2 w;
        w.x = pack2bf(va[X][Y][0], va[X][Y][1]);
        w.y = pack2bf(va[X][Y][2], va[X][Y][3]);
        *(uint2*)(vb + ((size_t)((b * 8 + hh) * CHC + (o & 31))) * CNS + Nx + g * 4) = w;
      }
    }
}

// -------- K7: MFMA flash attention, 2 chunks per barrier (r13 best) ----------
// Dual buffers x 2 chunk-slots: 8 barriers; slot-1 softmax VALU overlaps
// slot-0 PV MFMA. 16B-aligned pads (K rows 80B, V rows 144B).
// LDS 71.7KB -> 2 blocks/CU, 512 blocks = zero tail.
__launch_bounds__(512, 4)
__global__ void k_attn_mfma(const ushort* __restrict__ qb, const ushort* __restrict__ kb,
                            const ushort* __restrict__ vb, ushort* __restrict__ tmpb) {
  int bh = blockIdx.x >> 3;          // 64
  int mb = blockIdx.x & 7;           // 8 m-blocks of 256 rows
  int b = bh >> 3, h = bh & 7;
  int tid = threadIdx.x;
  int wid = tid >> 6, lane = tid & 63;
  int col = lane & 15, g = lane >> 4;
  int mA = mb * 256 + wid * 32 + col;    // tile A rows; tile B = +16

  __shared__ ushort Kst[2][2][64 * 40];  // [buf][slot] 80B rows
  __shared__ ushort Vst[2][2][32 * 72];  // [buf][slot] 144B rows
  __shared__ ushort plds[8][2048];       // dual 2KB P buffers per wave

  char* pwA = (char*)&plds[wid][0];
  char* pwB = (char*)&plds[wid][1024];
  int swz = (col & 7) << 4;
  int wb0 = col * 128 + g * 8;
  int rb0 = (col * 128 + g * 16) ^ swz;
  int rb1 = (col * 128 + 64 + g * 16) ^ swz;

  const ushort* qpA = qb + ((size_t)(b * CL + mA)) * CC + h * CHC + g * 8;
  short8 qfA = *(const short8*)qpA;
  short8 qfB = *(const short8*)(qpA + 16 * CC);

  const ushort* kglob = kb + (size_t)bh * 32768 + tid * 4;            // [n][c]
  const ushort* vglob = vb + (size_t)bh * 32768 + (tid >> 4) * 1024 + (tid & 15) * 4;  // [c][n]
  int kdst = (tid >> 3) * 40 + (tid & 7) * 4;
  int vdst = (tid >> 4) * 72 + (tid & 15) * 4;

  f32x4 oA0 = {0.f,0.f,0.f,0.f}, oA1 = {0.f,0.f,0.f,0.f};
  f32x4 oB0 = {0.f,0.f,0.f,0.f}, oB1 = {0.f,0.f,0.f,0.f};
  float lA = 0.f, lB = 0.f;

  // prologue: stage chunks 0,1 into buf 0
  {
    uint2 k0 = *(const uint2*)(kglob);
    uint2 k1 = *(const uint2*)(kglob + 2048);
    uint2 v0 = *(const uint2*)(vglob);
    uint2 v1 = *(const uint2*)(vglob + 64);
    *(uint2*)&Kst[0][0][kdst] = k0;
    *(uint2*)&Kst[0][1][kdst] = k1;
    *(uint2*)&Vst[0][0][vdst] = v0;
    *(uint2*)&Vst[0][1][vdst] = v1;
  }
  __syncthreads();

  int cur = 0;
  for (int it = 0; it < 8; it++) {
    uint2 kx0, kx1, vx0, vx1;
    if (it < 7) {
      int cb = (it + 1) * 2;
      kx0 = *(const uint2*)(kglob + (size_t)cb * 2048);
      kx1 = *(const uint2*)(kglob + (size_t)(cb + 1) * 2048);
      vx0 = *(const uint2*)(vglob + (size_t)cb * 64);
      vx1 = *(const uint2*)(vglob + (size_t)(cb + 1) * 64);
    }

    #pragma unroll
    for (int s = 0; s < 2; s++) {
      const ushort* Kc = &Kst[cur][s][0];
      const ushort* Vc = &Vst[cur][s][0];
      short8 kf0 = *(const short8*)(Kc + ( 0 + col) * 40 + g * 8);
      short8 kf1 = *(const short8*)(Kc + (16 + col) * 40 + g * 8);
      short8 kf2 = *(const short8*)(Kc + (32 + col) * 40 + g * 8);
      short8 kf3 = *(const short8*)(Kc + (48 + col) * 40 + g * 8);
      short8 vf00 = *(const short8*)(Vc + (col     ) * 72 +  0 + g * 8);
      short8 vf01 = *(const short8*)(Vc + (col     ) * 72 + 32 + g * 8);
      short8 vf10 = *(const short8*)(Vc + (col + 16) * 72 +  0 + g * 8);
      short8 vf11 = *(const short8*)(Vc + (col + 16) * 72 + 32 + g * 8);

      f32x4 zero = {0.f,0.f,0.f,0.f};
      f32x4 sA0 = __builtin_amdgcn_mfma_f32_16x16x32_bf16(kf0, qfA, zero, 0, 0, 0);
      f32x4 sA1 = __builtin_amdgcn_mfma_f32_16x16x32_bf16(kf1, qfA, zero, 0, 0, 0);
      f32x4 sA2 = __builtin_amdgcn_mfma_f32_16x16x32_bf16(kf2, qfA, zero, 0, 0, 0);
      f32x4 sA3 = __builtin_amdgcn_mfma_f32_16x16x32_bf16(kf3, qfA, zero, 0, 0, 0);
      f32x4 sB0 = __builtin_amdgcn_mfma_f32_16x16x32_bf16(kf0, qfB, zero, 0, 0, 0);
      f32x4 sB1 = __builtin_amdgcn_mfma_f32_16x16x32_bf16(kf1, qfB, zero, 0, 0, 0);
      f32x4 sB2 = __builtin_amdgcn_mfma_f32_16x16x32_bf16(kf2, qfB, zero, 0, 0, 0);
      f32x4 sB3 = __builtin_amdgcn_mfma_f32_16x16x32_bf16(kf3, qfB, zero, 0, 0, 0);

      {
        float ps = 0.f;
        #pragma unroll
        for (int f = 0; f < 4; f++) {
          f32x4 sv = (f == 0) ? sA0 : (f == 1) ? sA1 : (f == 2) ? sA2 : sA3;
          float p0 = __builtin_amdgcn_exp2f(sv[0]);
          float p1 = __builtin_amdgcn_exp2f(sv[1]);
          float p2 = __builtin_amdgcn_exp2f(sv[2]);
          float p3 = __builtin_amdgcn_exp2f(sv[3]);
          ps += (p0 + p1) + (p2 + p3);
          *(uint2*)(pwA + ((wb0 + f * 32) ^ swz)) = make_uint2(packtrunc(p0, p1), packtrunc(p2, p3));
        }
        lA += ps;
      }
      {
        float ps = 0.f;
        #pragma unroll
        for (int f = 0; f < 4; f++) {
          f32x4 sv = (f == 0) ? sB0 : (f == 1) ? sB1 : (f == 2) ? sB2 : sB3;
          float p0 = __builtin_amdgcn_exp2f(sv[0]);
          float p1 = __builtin_amdgcn_exp2f(sv[1]);
          float p2 = __builtin_amdgcn_exp2f(sv[2]);
          float p3 = __builtin_amdgcn_exp2f(sv[3]);
          ps += (p0 + p1) + (p2 + p3);
          *(uint2*)(pwB + ((wb0 + f * 32) ^ swz)) = make_uint2(packtrunc(p0, p1), packtrunc(p2, p3));
        }
        lB += ps;
      }

      short8 pfA0 = *(const short8*)(pwA + rb0);
      short8 pfA1 = *(const short8*)(pwA + rb1);
      short8 pfB0 = *(const short8*)(pwB + rb0);
      short8 pfB1 = *(const short8*)(pwB + rb1);

      oA0 = __builtin_amdgcn_mfma_f32_16x16x32_bf16(vf00, pfA0, oA0, 0, 0, 0);
      oA0 = __builtin_amdgcn_mfma_f32_16x16x32_bf16(vf01, pfA1, oA0, 0, 0, 0);
      oA1 = __builtin_amdgcn_mfma_f32_16x16x32_bf16(vf10, pfA0, oA1, 0, 0, 0);
      oA1 = __builtin_amdgcn_mfma_f32_16x16x32_bf16(vf11, pfA1, oA1, 0, 0, 0);
      oB0 = __builtin_amdgcn_mfma_f32_16x16x32_bf16(vf00, pfB0, oB0, 0, 0, 0);
      oB0 = __builtin_amdgcn_mfma_f32_16x16x32_bf16(vf01, pfB1, oB0, 0, 0, 0);
      oB1 = __builtin_amdgcn_mfma_f32_16x16x32_bf16(vf10, pfB0, oB1, 0, 0, 0);
      oB1 = __builtin_amdgcn_mfma_f32_16x16x32_bf16(vf11, pfB1, oB1, 0, 0, 0);
    }

    if (it < 7) {
      *(uint2*)&Kst[cur ^ 1][0][kdst] = kx0;
      *(uint2*)&Kst[cur ^ 1][1][kdst] = kx1;
      *(uint2*)&Vst[cur ^ 1][0][vdst] = vx0;
      *(uint2*)&Vst[cur ^ 1][1][vdst] = vx1;
    }
    __syncthreads();
    cur ^= 1;
  }

  lA += __shfl_xor(lA, 16); lA += __shfl_xor(lA, 32);
  lB += __shfl_xor(lB, 16); lB += __shfl_xor(lB, 32);
  float rlA = 1.f / lA, rlB = 1.f / lB;

  ushort* opA = tmpb + ((size_t)(b * CL + mA)) * CC + h * CHC;
  ushort* opB = opA + 16 * CC;
  {
    uint2 w0, w1;
    w0.x = pack2bf(oA0[0] * rlA, oA0[1] * rlA);
    w0.y = pack2bf(oA0[2] * rlA, oA0[3] * rlA);
    w1.x = pack2bf(oA1[0] * rlA, oA1[1] * rlA);
    w1.y = pack2bf(oA1[2] * rlA, oA1[3] * rlA);
    *(uint2*)(opA + g * 4) = w0;
    *(uint2*)(opA + 16 + g * 4) = w1;
  }
  {
    uint2 w0, w1;
    w0.x = pack2bf(oB0[0] * rlB, oB0[1] * rlB);
    w0.y = pack2bf(oB0[2] * rlB, oB0[3] * rlB);
    w1.x = pack2bf(oB1[0] * rlB, oB1[1] * rlB);
    w1.y = pack2bf(oB1[2] * rlB, oB1[3] * rlB);
    *(uint2*)(opB + g * 4) = w0;
    *(uint2*)(opB + 16 + g * 4) = w1;
  }
}

// ------- K8: y = tmp_bf @ Wo_bf^T + bo via MFMA (2 r-tiles x 8 o-tiles) -----
__launch_bounds__(256)
__global__ void k_yproj_mfma(const ushort* __restrict__ tmpb, const ushort* __restrict__ wob,
                             const float* __restrict__ bo, float* __restrict__ y) {
  int tid = threadIdx.x;
  int wid = tid >> 6, lane = tid & 63;
  int widx = blockIdx.x * 4 + wid;      // 1024 waves
  int rt2 = widx >> 1;                  // 512 row-pairs
  int og = widx & 1;                    // 2 o-groups of 128
  int col = lane & 15, g = lane >> 4;
  int R0 = rt2 * 32, O0 = og * 128;

  const ushort* ap0 = tmpb + ((size_t)(R0 + col)) * CC + g * 8;
  const ushort* ap1 = ap0 + (size_t)16 * CC;
  const ushort* bp = wob + (size_t)(O0 + col) * CC + g * 8;

  f32x4 acc[2][8];
  #pragma unroll
  for (int o4 = 0; o4 < 8; o4++) {
    float bb = bo[O0 + o4 * 16 + col];
    #pragma unroll
    for (int r = 0; r < 4; r++) { acc[0][o4][r] = bb; acc[1][o4][r] = bb; }
  }

  #pragma unroll
  for (int ks = 0; ks < 8; ks++) {
    short8 af0 = *(const short8*)(ap0 + ks * 32);
    short8 af1 = *(const short8*)(ap1 + ks * 32);
    #pragma unroll
    for (int o4 = 0; o4 < 8; o4++) {
      short8 bf = *(const short8*)(bp + (size_t)o4 * 16 * CC + ks * 32);
      acc[0][o4] = __builtin_amdgcn_mfma_f32_16x16x32_bf16(af0, bf, acc[0][o4], 0, 0, 0);
      acc[1][o4] = __builtin_amdgcn_mfma_f32_16x16x32_bf16(af1, bf, acc[1][o4], 0, 0, 0);
    }
  }

  #pragma unroll
  for (int rr = 0; rr < 2; rr++)
    #pragma unroll
    for (int o4 = 0; o4 < 8; o4++)
      #pragma unroll
      for (int r = 0; r < 4; r++)
        y[(size_t)(R0 + rr * 16 + g * 4 + r) * CC + O0 + o4 * 16 + col] = acc[rr][o4][r];
}

extern "C" void kernel_launch(void* const* d_in, const int* in_sizes, int n_in,
                              void* d_out, int out_size, void* d_ws, size_t ws_size,
                              hipStream_t stream) {
  const float* x    = (const float*)d_in[0];
  const float* q    = (const float*)d_in[1];
  const float* mask = (const float*)d_in[2];
  const float* Wq   = (const float*)d_in[3];
  const float* bq   = (const float*)d_in[4];
  const float* Wmod = (const float*)d_in[5];
  const float* dw_w = (const float*)d_in[6];
  const float* dw_b = (const float*)d_in[7];
  const float* ln_w = (const float*)d_in[8];
  const float* ln_b = (const float*)d_in[9];
  const float* offw = (const float*)d_in[10];
  const float* Wk   = (const float*)d_in[11];
  const float* bk   = (const float*)d_in[12];
  const float* Wv   = (const float*)d_in[13];
  const float* bv   = (const float*)d_in[14];
  const float* Wo   = (const float*)d_in[15];
  const float* bo   = (const float*)d_in[16];

  float* ws = (float*)d_ws;
  float* out = (float*)d_out;
  float* out_y   = out;
  float* out_pos = out + (size_t)CB * CL * CC;
  float* out_ref = out_pos + (size_t)CBG * CHW * 2;

  ushort* wmodb = (ushort*)(ws + WS_WMOD);
  ushort* xt    = (ushort*)(ws + WS_XT);
  ushort* qtb   = (ushort*)(ws + WS_QT);
  ushort* xst   = (ushort*)(ws + WS_XST);
  ushort* kbuf  = (ushort*)(ws + WS_KB);
  ushort* vbuf  = (ushort*)(ws + WS_VB);
  ushort* wkb   = (ushort*)(ws + WS_WB);
  ushort* wvb   = wkb + 65536;
  ushort* wob   = wkb + 131072;
  ushort* tmpb  = (ushort*)(ws + WS_TMPB);
  ushort* qbuf  = (ushort*)(ws + WS_QB);
  float*  part  = ws + WS_PART;
  float*  mpart = ws + WS_MPART;

  k_poolprep<<<480, 256, 0, stream>>>(q, mask, part, mpart, qbuf, x, Wk, Wv, Wo, xt, wkb);
  k_qcond<<<8, 256, 0, stream>>>(part, mpart, Wq, bq, ws + WS_QCOND);
  k_wprep<<<128, 256, 0, stream>>>(Wmod, ws + WS_QCOND, wmodb);
  k_mod_mfma<<<2048, 256, 0, stream>>>(wmodb, xt, qtb);
  k_off_sample<<<8192, 256, 0, stream>>>(qtb, dw_w, dw_b, ln_w, ln_b, offw, xt,
                                         out_pos, out_ref, xst);
  k_kv_mfma<<<512, 256, 0, stream>>>(xst, wkb, wvb, bk, bv, kbuf, vbuf);
  k_attn_mfma<<<512, 512, 0, stream>>>(qbuf, kbuf, vbuf, tmpb);
  k_yproj_mfma<<<256, 256, 0, stream>>>(tmpb, wob, bo, out_y);
}

// Round 16
// 118.958 us; speedup vs baseline: 1.0989x; 1.0640x over previous
//
#include <hip/hip_runtime.h>
#include <math.h>

typedef unsigned int uint;
typedef unsigned short ushort;
typedef __attribute__((ext_vector_type(8))) short short8;
typedef __attribute__((ext_vector_type(4))) float f32x4;

// Problem constants
constexpr int CB  = 8;      // batch B
constexpr int CL  = 2048;   // sequence length L
constexpr int CC  = 256;    // channels NC
constexpr int CHC = 32;     // head channels
constexpr int CGC = 32;     // group channels
constexpr int CHW = 1024;   // H*W (32*32)
constexpr int CNS = 1024;   // n_sample
constexpr int CBG = 64;     // B * n_groups

// Workspace layout (float offsets)
constexpr size_t WS_WMOD  = 4224;       // bf16 [8][256][256]  -> 266368
constexpr size_t WS_XT    = 266368;     // bf16 [2][1024][256] -> 528512
constexpr size_t WS_QT    = 528512;     // bf16 [8][1024][256] (hw-major) -> 1577088
constexpr size_t WS_XST   = 2756736;    // bf16 [8][1024][256] -> 3805312
constexpr size_t WS_KB    = 3805312;    // bf16 [64][1024][32] -> 4853888
constexpr size_t WS_VB    = 4853888;    // bf16 [64][32][1024] -> 5902464
constexpr size_t WS_WB    = 5902464;    // bf16 Wk,Wv,Wo -> 6000768
constexpr size_t WS_TMPB  = 6000768;    // bf16 [8][2048][256] -> 8097920
constexpr size_t WS_QB    = 8097920;    // bf16 [8][2048][256] -> 10195072
constexpr size_t WS_PART  = 10195072;   // f32 [8][32][256] pooling partials -> 10260608
constexpr size_t WS_MPART = 10260608;   // f32 [8][32] mask partials -> 10260864

static __device__ __forceinline__ ushort f2bf(float f) {
  uint u = __float_as_uint(f);
  return (ushort)((u + 0x7FFFu + ((u >> 16) & 1u)) >> 16);
}
static __device__ __forceinline__ float bf2f(ushort u) {
  return __uint_as_float((uint)u << 16);
}
static __device__ __forceinline__ uint pack2bf(float a, float b) {
  return (uint)f2bf(a) | ((uint)f2bf(b) << 16);
}
// truncating bf16 pack of two floats in one v_perm_b32
static __device__ __forceinline__ uint packtrunc(float lo, float hi) {
  return __builtin_amdgcn_perm(__float_as_uint(hi), __float_as_uint(lo), 0x07060302u);
}

// --- K1: merged — pool partials + q->bf16 | x->x^T bf16 | W->bf16 -----------
__global__ void k_poolprep(const float* __restrict__ q, const float* __restrict__ mask,
                           float* __restrict__ part, float* __restrict__ mpart,
                           ushort* __restrict__ qb,
                           const float* __restrict__ x, const float* __restrict__ Wk,
                           const float* __restrict__ Wv, const float* __restrict__ Wo,
                           ushort* __restrict__ xt, ushort* __restrict__ wb) {
  int bid = blockIdx.x;
  int tid = threadIdx.x;
  __shared__ float shbuf[64 * 65];
  if (bid < 256) {
    int b  = bid >> 5;
    int lc = bid & 31;
    int l0 = lc * 64;
    const float scale = 0.17677669529663687f * 1.4426950408889634f;  // 32^-.5 * log2e
    float* mloc = shbuf;
    if (tid < 64) mloc[tid] = mask[b * CL + l0 + tid];
    __syncthreads();
    if (tid == 0) {
      float s = 0.f;
      for (int j = 0; j < 64; j++) s += mloc[j];
      mpart[b * 32 + lc] = s;
    }
    float acc = 0.f;
    const float* qp = q + (size_t)(b * CL + l0) * CC + tid;
    ushort* qw = qb + (size_t)(b * CL + l0) * CC + tid;
    for (int j = 0; j < 64; j++) {
      float v = qp[(size_t)j * CC];
      acc += v * mloc[j];
      qw[(size_t)j * CC] = f2bf(v * scale);
    }
    part[((size_t)(b * 32 + lc)) * CC + tid] = acc;
  } else if (bid < 384) {
    int b2 = bid - 256;
    int ref  = b2 >> 6;
    int cblk = (b2 >> 4) & 3;
    int hwblk = b2 & 15;
    float (*t)[65] = (float(*)[65])shbuf;
    int c0 = cblk * 64, hw0 = hwblk * 64;
    const float* src = x + (size_t)ref * CC * CHW;
    int hl = tid & 63, cq = tid >> 6;
    #pragma unroll
    for (int r = 0; r < 16; r++) {
      int cl = cq * 16 + r;
      t[cl][hl] = src[(size_t)(c0 + cl) * CHW + hw0 + hl];
    }
    __syncthreads();
    int cl2 = tid & 63, hq = tid >> 6;
    #pragma unroll
    for (int r = 0; r < 16; r++) {
      int hwl = hq * 16 + r;
      xt[((size_t)(ref * CHW + hw0 + hwl)) * CC + c0 + cl2] = f2bf(t[cl2][hwl]);
    }
  } else {
    int t2 = (bid - 384) * 256 + tid;
    int which = t2 >> 13;
    size_t off = ((size_t)(t2 & 8191)) * 8;
    const float* src = (which == 0) ? Wk : (which == 1) ? Wv : Wo;
    float4 a = *(const float4*)(src + off);
    float4 b = *(const float4*)(src + off + 4);
    uint4 r;
    r.x = pack2bf(a.x, a.y); r.y = pack2bf(a.z, a.w);
    r.z = pack2bf(b.x, b.y); r.w = pack2bf(b.z, b.w);
    *(uint4*)(wb + (size_t)which * 65536 + off) = r;
  }
}

// -- K2: fused qcond + modulated/demodulated weights -> bf16 ------------------
// Each block recomputes q_cond for its batch (cheap: 65K MACs, Wq L2-hot),
// eliminating the separate 8-block k_qcond launch + its dependency stall.
__global__ void k_wprep(const float* __restrict__ part, const float* __restrict__ mpart,
                        const float* __restrict__ Wq, const float* __restrict__ bq,
                        const float* __restrict__ Wmod, ushort* __restrict__ wmodb) {
  int b  = blockIdx.x >> 4;
  int og = blockIdx.x & 15;
  int tid = threadIdx.x;
  __shared__ float qm[CC];
  __shared__ float qcond_s[CC];
  __shared__ float msh;

  // reduce pooling partials for this batch
  float s = 0.f;
  const float* pp = part + (size_t)b * 32 * CC + tid;
  #pragma unroll
  for (int lc = 0; lc < 32; lc++) s += pp[(size_t)lc * CC];
  if (tid < 32) {
    float m = mpart[b * 32 + tid];
    #pragma unroll
    for (int k = 1; k < 32; k <<= 1) m += __shfl_xor(m, k, 32);
    if (tid == 0) msh = m;
  }
  __syncthreads();
  qm[tid] = s * (1.f / (msh + 1e-6f));
  __syncthreads();
  // q_cond[b][tid] = bq + Wq row . qm
  float qc = bq[tid];
  const float* wrow = Wq + (size_t)tid * CC;
  for (int i = 0; i < CC; i++) qc += wrow[i] * qm[i];
  qcond_s[tid] = qc;
  __syncthreads();

  int ol = tid >> 4, seg = tid & 15;
  int o = og * 16 + ol;
  const float* wr = Wmod + (size_t)o * CC + seg * 16;
  float m[16];
  float ss = 0.f;
  #pragma unroll
  for (int j = 0; j < 16; j++) {
    float v = wr[j] * (qcond_s[seg * 16 + j] + 1.f);
    m[j] = v;
    ss += v * v;
  }
  #pragma unroll
  for (int k = 1; k < 16; k <<= 1) ss += __shfl_xor(ss, k, 16);
  float d = rsqrtf(ss + 1e-8f);
  uint u[8];
  #pragma unroll
  for (int j = 0; j < 8; j++) u[j] = pack2bf(m[2 * j] * d, m[2 * j + 1] * d);
  ushort* dst = wmodb + ((size_t)(b * CC + o)) * CC + seg * 16;
  *(uint4*)(dst)     = make_uint4(u[0], u[1], u[2], u[3]);
  *(uint4*)(dst + 8) = make_uint4(u[4], u[5], u[6], u[7]);
}

// --- K3: modulated 1x1 conv via MFMA, 2 ot x 2 hwt per wave -> qt bf16 ------
__launch_bounds__(256)
__global__ void k_mod_mfma(const ushort* __restrict__ wmodb, const ushort* __restrict__ xt,
                           ushort* __restrict__ qtb) {
  int tid = threadIdx.x;
  int wid = tid >> 6, lane = tid & 63;
  int widx = blockIdx.x * 4 + wid;     // 2048 waves
  int b   = widx >> 8;                 // 8
  int og  = (widx >> 5) & 7;           // 8 o-pairs
  int hg  = widx & 31;                 // 32 hw-pairs
  int col = lane & 15, g = lane >> 4;
  int O0 = og * 32, HW0 = hg * 32;
  const ushort* ap0 = wmodb + ((size_t)(b * CC + O0 + col)) * CC + g * 8;
  const ushort* ap1 = ap0 + (size_t)16 * CC;
  const ushort* bp0 = xt + ((size_t)((b & 1) * CHW + HW0 + col)) * CC + g * 8;
  const ushort* bp1 = bp0 + (size_t)16 * CC;
  f32x4 acc[2][2];
  #pragma unroll
  for (int X = 0; X < 2; X++)
    #pragma unroll
    for (int Y = 0; Y < 2; Y++)
      acc[X][Y] = (f32x4){0.f, 0.f, 0.f, 0.f};
  #pragma unroll
  for (int ks = 0; ks < 8; ks++) {
    short8 af0 = *(const short8*)(ap0 + ks * 32);
    short8 af1 = *(const short8*)(ap1 + ks * 32);
    short8 bf0 = *(const short8*)(bp0 + ks * 32);
    short8 bf1 = *(const short8*)(bp1 + ks * 32);
    acc[0][0] = __builtin_amdgcn_mfma_f32_16x16x32_bf16(af0, bf0, acc[0][0], 0, 0, 0);
    acc[0][1] = __builtin_amdgcn_mfma_f32_16x16x32_bf16(af0, bf1, acc[0][1], 0, 0, 0);
    acc[1][0] = __builtin_amdgcn_mfma_f32_16x16x32_bf16(af1, bf0, acc[1][0], 0, 0, 0);
    acc[1][1] = __builtin_amdgcn_mfma_f32_16x16x32_bf16(af1, bf1, acc[1][1], 0, 0, 0);
  }
  #pragma unroll
  for (int X = 0; X < 2; X++)
    #pragma unroll
    for (int Y = 0; Y < 2; Y++) {
      uint2 st;
      st.x = pack2bf(acc[X][Y][0], acc[X][Y][1]);
      st.y = pack2bf(acc[X][Y][2], acc[X][Y][3]);
      *(uint2*)(qtb + ((size_t)(b * CHW + HW0 + Y * 16 + col)) * CC + O0 + X * 16 + g * 4) = st;
    }
}

// -- K4: dwconv3x3 + LN + GELU + offset + tanh + ref -> pos -> grid sample ---
__global__ void k_off_sample(const ushort* __restrict__ qtb, const float* __restrict__ dww,
                             const float* __restrict__ dwb, const float* __restrict__ lnw,
                             const float* __restrict__ lnb, const float* __restrict__ offw,
                             const ushort* __restrict__ xt,
                             float* __restrict__ out_pos, float* __restrict__ out_ref,
                             ushort* __restrict__ xst) {
  int bg   = blockIdx.x >> 7;
  int pblk = blockIdx.x & 127;
  int tid  = threadIdx.x;
  int c = tid & 31, pp = tid >> 5;
  int p0 = pblk * 8;
  int yy = p0 >> 5;
  int xx = (p0 & 31) + pp;
  int p  = p0 + pp;
  const ushort* src = qtb + ((size_t)(bg >> 3) * CHW) * CC + (bg & 7) * CGC + c;
  float acc = dwb[c];
  #pragma unroll
  for (int ky = 0; ky < 3; ky++) {
    int yr = yy + ky - 1;
    if (yr < 0 || yr > 31) continue;
    #pragma unroll
    for (int kx = 0; kx < 3; kx++) {
      int xc = xx + kx - 1;
      if (xc < 0 || xc > 31) continue;
      acc += dww[c * 9 + ky * 3 + kx] * bf2f(src[(size_t)(yr * 32 + xc) * CC]);
    }
  }
  float s1 = acc, s2 = acc * acc;
  #pragma unroll
  for (int m = 1; m < 32; m <<= 1) { s1 += __shfl_xor(s1, m, 32); s2 += __shfl_xor(s2, m, 32); }
  float mu  = s1 * (1.f / 32.f);
  float var = s2 * (1.f / 32.f) - mu * mu;
  float tn  = (acc - mu) * rsqrtf(var + 1e-5f) * lnw[c] + lnb[c];
  float g   = 0.5f * tn * (1.f + erff(tn * 0.70710678118654752f));
  float sy = offw[c] * g, sx = offw[32 + c] * g;
  #pragma unroll
  for (int m = 1; m < 32; m <<= 1) { sy += __shfl_xor(sy, m, 32); sx += __shfl_xor(sx, m, 32); }

  float mine  = tanhf((c & 1) ? sx : sy);
  float other = __shfl_xor(mine, 1, 32);
  float ty = (c & 1) ? other : mine;
  float tx = (c & 1) ? mine : other;

  float refy = (0.5f + (float)yy) * (2.f / 31.f) - 1.f;
  float refx = (0.5f + (float)xx) * (2.f / 31.f) - 1.f;
  float py = ty * (2.f / 31.f) + refy;
  float px = tx * (2.f / 31.f) + refx;
  if (c < 2) {
    int oidx = bg * 2048 + p * 2 + c;
    out_pos[oidx] = (c == 0) ? py : px;
    out_ref[oidx] = (c == 0) ? refy : refx;
  }

  float gx = (px + 1.f) * 15.5f;
  float gy = (py + 1.f) * 15.5f;
  float x0f = floorf(gx), y0f = floorf(gy);
  float wx = gx - x0f, wy = gy - y0f;
  int ix0 = (int)x0f, iy0 = (int)y0f;
  const ushort* img = xt + (size_t)(((bg >> 3) & 1)) * CHW * CC + (bg & 7) * CGC + c;
  float sacc = 0.f;
  #pragma unroll
  for (int dy = 0; dy < 2; dy++) {
    int iy = iy0 + dy;
    if (iy < 0 || iy > 31) continue;
    float wyv = dy ? wy : 1.f - wy;
    #pragma unroll
    for (int dx = 0; dx < 2; dx++) {
      int ix = ix0 + dx;
      if (ix < 0 || ix > 31) continue;
      float wxv = dx ? wx : 1.f - wx;
      sacc += wyv * wxv * bf2f(img[(size_t)(iy * 32 + ix) * CC]);
    }
  }
  xst[((size_t)((bg >> 3) * CNS) + p) * CC + (bg & 7) * CGC + c] = f2bf(sacc);
}

// -------- K6: fused K/V projection via MFMA, 2 nt x 2 ot per wave -----------
__launch_bounds__(256)
__global__ void k_kv_mfma(const ushort* __restrict__ xst, const ushort* __restrict__ wkb,
                          const ushort* __restrict__ wvb, const float* __restrict__ bk,
                          const float* __restrict__ bv, ushort* __restrict__ kb,
                          ushort* __restrict__ vb) {
  int tid = threadIdx.x;
  int wid = tid >> 6, lane = tid & 63;
  int widx = blockIdx.x * 4 + wid;       // 2048 waves
  int b   = widx >> 8;                   // 8
  int ntg = (widx >> 3) & 31;            // 32 nt-pairs
  int otg = widx & 7;                    // 8 ot-pairs
  int col = lane & 15, g = lane >> 4;
  int N0 = ntg * 32, O0 = otg * 32;

  const ushort* xs0 = xst + ((size_t)(b * CNS + N0 + col)) * CC + g * 8;
  const ushort* xs1 = xs0 + (size_t)16 * CC;
  const ushort* wk0 = wkb + (size_t)(O0 + col) * CC + g * 8;
  const ushort* wk1 = wk0 + (size_t)16 * CC;
  const ushort* wv0 = wvb + (size_t)(O0 + col) * CC + g * 8;
  const ushort* wv1 = wv0 + (size_t)16 * CC;

  f32x4 ka[2][2], va[2][2];
  #pragma unroll
  for (int Y = 0; Y < 2; Y++) {
    float bvv = bv[O0 + Y * 16 + col];
    #pragma unroll
    for (int r = 0; r < 4; r++) {
      float bkv = bk[O0 + Y * 16 + g * 4 + r];
      ka[0][Y][r] = bkv; ka[1][Y][r] = bkv;
      va[0][Y][r] = bvv; va[1][Y][r] = bvv;
    }
  }

  #pragma unroll
  for (int ks = 0; ks < 8; ks++) {
    short8 xf0 = *(const short8*)(xs0 + ks * 32);
    short8 xf1 = *(const short8*)(xs1 + ks * 32);
    short8 kf0 = *(const short8*)(wk0 + ks * 32);
    short8 kf1 = *(const short8*)(wk1 + ks * 32);
    short8 vf0 = *(const short8*)(wv0 + ks * 32);
    short8 vf1 = *(const short8*)(wv1 + ks * 32);
    ka[0][0] = __builtin_amdgcn_mfma_f32_16x16x32_bf16(kf0, xf0, ka[0][0], 0, 0, 0);
    ka[0][1] = __builtin_amdgcn_mfma_f32_16x16x32_bf16(kf1, xf0, ka[0][1], 0, 0, 0);
    ka[1][0] = __builtin_amdgcn_mfma_f32_16x16x32_bf16(kf0, xf1, ka[1][0], 0, 0, 0);
    ka[1][1] = __builtin_amdgcn_mfma_f32_16x16x32_bf16(kf1, xf1, ka[1][1], 0, 0, 0);
    va[0][0] = __builtin_amdgcn_mfma_f32_16x16x32_bf16(xf0, vf0, va[0][0], 0, 0, 0);
    va[0][1] = __builtin_amdgcn_mfma_f32_16x16x32_bf16(xf0, vf1, va[0][1], 0, 0, 0);
    va[1][0] = __builtin_amdgcn_mfma_f32_16x16x32_bf16(xf1, vf0, va[1][0], 0, 0, 0);
    va[1][1] = __builtin_amdgcn_mfma_f32_16x16x32_bf16(xf1, vf1, va[1][1], 0, 0, 0);
  }

  #pragma unroll
  for (int X = 0; X < 2; X++)
    #pragma unroll
    for (int Y = 0; Y < 2; Y++) {
      int Oy = O0 + Y * 16, Nx = N0 + X * 16;
      {
        int hh = Oy >> 5;
        int c0 = (Oy & 31) + g * 4;
        uint2 w;
        w.x = pack2bf(ka[X][Y][0], ka[X][Y][1]);
        w.y = pack2bf(ka[X][Y][2], ka[X][Y][3]);
        *(uint2*)(kb + ((size_t)((b * 8 + hh) * CNS + Nx + col)) * CHC + c0) = w;
      }
      {
        int o = Oy + col;
        int hh = o >> 5;
        uint2 w;
        w.x = pack2bf(va[X][Y][0], va[X][Y][1]);
        w.y = pack2bf(va[X][Y][2], va[X][Y][3]);
        *(uint2*)(vb + ((size_t)((b * 8 + hh) * CHC + (o & 31))) * CNS + Nx + g * 4) = w;
      }
    }
}

// -------- K7: MFMA flash attention, 2 chunks per barrier (r13 best) ----------
__launch_bounds__(512, 4)
__global__ void k_attn_mfma(const ushort* __restrict__ qb, const ushort* __restrict__ kb,
                            const ushort* __restrict__ vb, ushort* __restrict__ tmpb) {
  int bh = blockIdx.x >> 3;          // 64
  int mb = blockIdx.x & 7;           // 8 m-blocks of 256 rows
  int b = bh >> 3, h = bh & 7;
  int tid = threadIdx.x;
  int wid = tid >> 6, lane = tid & 63;
  int col = lane & 15, g = lane >> 4;
  int mA = mb * 256 + wid * 32 + col;    // tile A rows; tile B = +16

  __shared__ ushort Kst[2][2][64 * 40];  // [buf][slot] 80B rows
  __shared__ ushort Vst[2][2][32 * 72];  // [buf][slot] 144B rows
  __shared__ ushort plds[8][2048];       // dual 2KB P buffers per wave

  char* pwA = (char*)&plds[wid][0];
  char* pwB = (char*)&plds[wid][1024];
  int swz = (col & 7) << 4;
  int wb0 = col * 128 + g * 8;
  int rb0 = (col * 128 + g * 16) ^ swz;
  int rb1 = (col * 128 + 64 + g * 16) ^ swz;

  const ushort* qpA = qb + ((size_t)(b * CL + mA)) * CC + h * CHC + g * 8;
  short8 qfA = *(const short8*)qpA;
  short8 qfB = *(const short8*)(qpA + 16 * CC);

  const ushort* kglob = kb + (size_t)bh * 32768 + tid * 4;            // [n][c]
  const ushort* vglob = vb + (size_t)bh * 32768 + (tid >> 4) * 1024 + (tid & 15) * 4;  // [c][n]
  int kdst = (tid >> 3) * 40 + (tid & 7) * 4;
  int vdst = (tid >> 4) * 72 + (tid & 15) * 4;

  f32x4 oA0 = {0.f,0.f,0.f,0.f}, oA1 = {0.f,0.f,0.f,0.f};
  f32x4 oB0 = {0.f,0.f,0.f,0.f}, oB1 = {0.f,0.f,0.f,0.f};
  float lA = 0.f, lB = 0.f;

  {
    uint2 k0 = *(const uint2*)(kglob);
    uint2 k1 = *(const uint2*)(kglob + 2048);
    uint2 v0 = *(const uint2*)(vglob);
    uint2 v1 = *(const uint2*)(vglob + 64);
    *(uint2*)&Kst[0][0][kdst] = k0;
    *(uint2*)&Kst[0][1][kdst] = k1;
    *(uint2*)&Vst[0][0][vdst] = v0;
    *(uint2*)&Vst[0][1][vdst] = v1;
  }
  __syncthreads();

  int cur = 0;
  for (int it = 0; it < 8; it++) {
    uint2 kx0, kx1, vx0, vx1;
    if (it < 7) {
      int cb = (it + 1) * 2;
      kx0 = *(const uint2*)(kglob + (size_t)cb * 2048);
      kx1 = *(const uint2*)(kglob + (size_t)(cb + 1) * 2048);
      vx0 = *(const uint2*)(vglob + (size_t)cb * 64);
      vx1 = *(const uint2*)(vglob + (size_t)(cb + 1) * 64);
    }

    #pragma unroll
    for (int s = 0; s < 2; s++) {
      const ushort* Kc = &Kst[cur][s][0];
      const ushort* Vc = &Vst[cur][s][0];
      short8 kf0 = *(const short8*)(Kc + ( 0 + col) * 40 + g * 8);
      short8 kf1 = *(const short8*)(Kc + (16 + col) * 40 + g * 8);
      short8 kf2 = *(const short8*)(Kc + (32 + col) * 40 + g * 8);
      short8 kf3 = *(const short8*)(Kc + (48 + col) * 40 + g * 8);
      short8 vf00 = *(const short8*)(Vc + (col     ) * 72 +  0 + g * 8);
      short8 vf01 = *(const short8*)(Vc + (col     ) * 72 + 32 + g * 8);
      short8 vf10 = *(const short8*)(Vc + (col + 16) * 72 +  0 + g * 8);
      short8 vf11 = *(const short8*)(Vc + (col + 16) * 72 + 32 + g * 8);

      f32x4 zero = {0.f,0.f,0.f,0.f};
      f32x4 sA0 = __builtin_amdgcn_mfma_f32_16x16x32_bf16(kf0, qfA, zero, 0, 0, 0);
      f32x4 sA1 = __builtin_amdgcn_mfma_f32_16x16x32_bf16(kf1, qfA, zero, 0, 0, 0);
      f32x4 sA2 = __builtin_amdgcn_mfma_f32_16x16x32_bf16(kf2, qfA, zero, 0, 0, 0);
      f32x4 sA3 = __builtin_amdgcn_mfma_f32_16x16x32_bf16(kf3, qfA, zero, 0, 0, 0);
      f32x4 sB0 = __builtin_amdgcn_mfma_f32_16x16x32_bf16(kf0, qfB, zero, 0, 0, 0);
      f32x4 sB1 = __builtin_amdgcn_mfma_f32_16x16x32_bf16(kf1, qfB, zero, 0, 0, 0);
      f32x4 sB2 = __builtin_amdgcn_mfma_f32_16x16x32_bf16(kf2, qfB, zero, 0, 0, 0);
      f32x4 sB3 = __builtin_amdgcn_mfma_f32_16x16x32_bf16(kf3, qfB, zero, 0, 0, 0);

      {
        float ps = 0.f;
        #pragma unroll
        for (int f = 0; f < 4; f++) {
          f32x4 sv = (f == 0) ? sA0 : (f == 1) ? sA1 : (f == 2) ? sA2 : sA3;
          float p0 = __builtin_amdgcn_exp2f(sv[0]);
          float p1 = __builtin_amdgcn_exp2f(sv[1]);
          float p2 = __builtin_amdgcn_exp2f(sv[2]);
          float p3 = __builtin_amdgcn_exp2f(sv[3]);
          ps += (p0 + p1) + (p2 + p3);
          *(uint2*)(pwA + ((wb0 + f * 32) ^ swz)) = make_uint2(packtrunc(p0, p1), packtrunc(p2, p3));
        }
        lA += ps;
      }
      {
        float ps = 0.f;
        #pragma unroll
        for (int f = 0; f < 4; f++) {
          f32x4 sv = (f == 0) ? sB0 : (f == 1) ? sB1 : (f == 2) ? sB2 : sB3;
          float p0 = __builtin_amdgcn_exp2f(sv[0]);
          float p1 = __builtin_amdgcn_exp2f(sv[1]);
          float p2 = __builtin_amdgcn_exp2f(sv[2]);
          float p3 = __builtin_amdgcn_exp2f(sv[3]);
          ps += (p0 + p1) + (p2 + p3);
          *(uint2*)(pwB + ((wb0 + f * 32) ^ swz)) = make_uint2(packtrunc(p0, p1), packtrunc(p2, p3));
        }
        lB += ps;
      }

      short8 pfA0 = *(const short8*)(pwA + rb0);
      short8 pfA1 = *(const short8*)(pwA + rb1);
      short8 pfB0 = *(const short8*)(pwB + rb0);
      short8 pfB1 = *(const short8*)(pwB + rb1);

      oA0 = __builtin_amdgcn_mfma_f32_16x16x32_bf16(vf00, pfA0, oA0, 0, 0, 0);
      oA0 = __builtin_amdgcn_mfma_f32_16x16x32_bf16(vf01, pfA1, oA0, 0, 0, 0);
      oA1 = __builtin_amdgcn_mfma_f32_16x16x32_bf16(vf10, pfA0, oA1, 0, 0, 0);
      oA1 = __builtin_amdgcn_mfma_f32_16x16x32_bf16(vf11, pfA1, oA1, 0, 0, 0);
      oB0 = __builtin_amdgcn_mfma_f32_16x16x32_bf16(vf00, pfB0, oB0, 0, 0, 0);
      oB0 = __builtin_amdgcn_mfma_f32_16x16x32_bf16(vf01, pfB1, oB0, 0, 0, 0);
      oB1 = __builtin_amdgcn_mfma_f32_16x16x32_bf16(vf10, pfB0, oB1, 0, 0, 0);
      oB1 = __builtin_amdgcn_mfma_f32_16x16x32_bf16(vf11, pfB1, oB1, 0, 0, 0);
    }

    if (it < 7) {
      *(uint2*)&Kst[cur ^ 1][0][kdst] = kx0;
      *(uint2*)&Kst[cur ^ 1][1][kdst] = kx1;
      *(uint2*)&Vst[cur ^ 1][0][vdst] = vx0;
      *(uint2*)&Vst[cur ^ 1][1][vdst] = vx1;
    }
    __syncthreads();
    cur ^= 1;
  }

  lA += __shfl_xor(lA, 16); lA += __shfl_xor(lA, 32);
  lB += __shfl_xor(lB, 16); lB += __shfl_xor(lB, 32);
  float rlA = 1.f / lA, rlB = 1.f / lB;

  ushort* opA = tmpb + ((size_t)(b * CL + mA)) * CC + h * CHC;
  ushort* opB = opA + 16 * CC;
  {
    uint2 w0, w1;
    w0.x = pack2bf(oA0[0] * rlA, oA0[1] * rlA);
    w0.y = pack2bf(oA0[2] * rlA, oA0[3] * rlA);
    w1.x = pack2bf(oA1[0] * rlA, oA1[1] * rlA);
    w1.y = pack2bf(oA1[2] * rlA, oA1[3] * rlA);
    *(uint2*)(opA + g * 4) = w0;
    *(uint2*)(opA + 16 + g * 4) = w1;
  }
  {
    uint2 w0, w1;
    w0.x = pack2bf(oB0[0] * rlB, oB0[1] * rlB);
    w0.y = pack2bf(oB0[2] * rlB, oB0[3] * rlB);
    w1.x = pack2bf(oB1[0] * rlB, oB1[1] * rlB);
    w1.y = pack2bf(oB1[2] * rlB, oB1[3] * rlB);
    *(uint2*)(opB + g * 4) = w0;
    *(uint2*)(opB + 16 + g * 4) = w1;
  }
}

// ------- K8: y = tmp_bf @ Wo_bf^T + bo via MFMA (2 r-tiles x 8 o-tiles) -----
__launch_bounds__(256)
__global__ void k_yproj_mfma(const ushort* __restrict__ tmpb, const ushort* __restrict__ wob,
                             const float* __restrict__ bo, float* __restrict__ y) {
  int tid = threadIdx.x;
  int wid = tid >> 6, lane = tid & 63;
  int widx = blockIdx.x * 4 + wid;      // 1024 waves
  int rt2 = widx >> 1;                  // 512 row-pairs
  int og = widx & 1;                    // 2 o-groups of 128
  int col = lane & 15, g = lane >> 4;
  int R0 = rt2 * 32, O0 = og * 128;

  const ushort* ap0 = tmpb + ((size_t)(R0 + col)) * CC + g * 8;
  const ushort* ap1 = ap0 + (size_t)16 * CC;
  const ushort* bp = wob + (size_t)(O0 + col) * CC + g * 8;

  f32x4 acc[2][8];
  #pragma unroll
  for (int o4 = 0; o4 < 8; o4++) {
    float bb = bo[O0 + o4 * 16 + col];
    #pragma unroll
    for (int r = 0; r < 4; r++) { acc[0][o4][r] = bb; acc[1][o4][r] = bb; }
  }

  #pragma unroll
  for (int ks = 0; ks < 8; ks++) {
    short8 af0 = *(const short8*)(ap0 + ks * 32);
    short8 af1 = *(const short8*)(ap1 + ks * 32);
    #pragma unroll
    for (int o4 = 0; o4 < 8; o4++) {
      short8 bf = *(const short8*)(bp + (size_t)o4 * 16 * CC + ks * 32);
      acc[0][o4] = __builtin_amdgcn_mfma_f32_16x16x32_bf16(af0, bf, acc[0][o4], 0, 0, 0);
      acc[1][o4] = __builtin_amdgcn_mfma_f32_16x16x32_bf16(af1, bf, acc[1][o4], 0, 0, 0);
    }
  }

  #pragma unroll
  for (int rr = 0; rr < 2; rr++)
    #pragma unroll
    for (int o4 = 0; o4 < 8; o4++)
      #pragma unroll
      for (int r = 0; r < 4; r++)
        y[(size_t)(R0 + rr * 16 + g * 4 + r) * CC + O0 + o4 * 16 + col] = acc[rr][o4][r];
}

extern "C" void kernel_launch(void* const* d_in, const int* in_sizes, int n_in,
                              void* d_out, int out_size, void* d_ws, size_t ws_size,
                              hipStream_t stream) {
  const float* x    = (const float*)d_in[0];
  const float* q    = (const float*)d_in[1];
  const float* mask = (const float*)d_in[2];
  const float* Wq   = (const float*)d_in[3];
  const float* bq   = (const float*)d_in[4];
  const float* Wmod = (const float*)d_in[5];
  const float* dw_w = (const float*)d_in[6];
  const float* dw_b = (const float*)d_in[7];
  const float* ln_w = (const float*)d_in[8];
  const float* ln_b = (const float*)d_in[9];
  const float* offw = (const float*)d_in[10];
  const float* Wk   = (const float*)d_in[11];
  const float* bk   = (const float*)d_in[12];
  const float* Wv   = (const float*)d_in[13];
  const float* bv   = (const float*)d_in[14];
  const float* Wo   = (const float*)d_in[15];
  const float* bo   = (const float*)d_in[16];

  float* ws = (float*)d_ws;
  float* out = (float*)d_out;
  float* out_y   = out;
  float* out_pos = out + (size_t)CB * CL * CC;
  float* out_ref = out_pos + (size_t)CBG * CHW * 2;

  ushort* wmodb = (ushort*)(ws + WS_WMOD);
  ushort* xt    = (ushort*)(ws + WS_XT);
  ushort* qtb   = (ushort*)(ws + WS_QT);
  ushort* xst   = (ushort*)(ws + WS_XST);
  ushort* kbuf  = (ushort*)(ws + WS_KB);
  ushort* vbuf  = (ushort*)(ws + WS_VB);
  ushort* wkb   = (ushort*)(ws + WS_WB);
  ushort* wvb   = wkb + 65536;
  ushort* wob   = wkb + 131072;
  ushort* tmpb  = (ushort*)(ws + WS_TMPB);
  ushort* qbuf  = (ushort*)(ws + WS_QB);
  float*  part  = ws + WS_PART;
  float*  mpart = ws + WS_MPART;

  k_poolprep<<<480, 256, 0, stream>>>(q, mask, part, mpart, qbuf, x, Wk, Wv, Wo, xt, wkb);
  k_wprep<<<128, 256, 0, stream>>>(part, mpart, Wq, bq, Wmod, wmodb);
  k_mod_mfma<<<512, 256, 0, stream>>>(wmodb, xt, qtb);
  k_off_sample<<<8192, 256, 0, stream>>>(qtb, dw_w, dw_b, ln_w, ln_b, offw, xt,
                                         out_pos, out_ref, xst);
  k_kv_mfma<<<512, 256, 0, stream>>>(xst, wkb, wvb, bk, bv, kbuf, vbuf);
  k_attn_mfma<<<512, 512, 0, stream>>>(qbuf, kbuf, vbuf, tmpb);
  k_yproj_mfma<<<256, 256, 0, stream>>>(tmpb, wob, bo, out_y);
}

// Round 17
// 118.427 us; speedup vs baseline: 1.1038x; 1.0045x over previous
//
#include <hip/hip_runtime.h>
#include <math.h>

typedef unsigned int uint;
typedef unsigned short ushort;
typedef __attribute__((ext_vector_type(8))) short short8;
typedef __attribute__((ext_vector_type(4))) float f32x4;

// Problem constants
constexpr int CB  = 8;      // batch B
constexpr int CL  = 2048;   // sequence length L
constexpr int CC  = 256;    // channels NC
constexpr int CHC = 32;     // head channels
constexpr int CGC = 32;     // group channels
constexpr int CHW = 1024;   // H*W (32*32)
constexpr int CNS = 1024;   // n_sample
constexpr int CBG = 64;     // B * n_groups

// Workspace layout (float offsets)
constexpr size_t WS_WMOD  = 4224;       // bf16 [8][256][256]  -> 266368
constexpr size_t WS_XT    = 266368;     // bf16 [2][1024][256] -> 528512
constexpr size_t WS_QT    = 528512;     // bf16 [8][1024][256] (hw-major) -> 1577088
constexpr size_t WS_XST   = 2756736;    // bf16 [8][1024][256] -> 3805312
constexpr size_t WS_KB    = 3805312;    // bf16 [64][1024][32] -> 4853888
constexpr size_t WS_VB    = 4853888;    // bf16 [64][32][1024] -> 5902464
constexpr size_t WS_WB    = 5902464;    // bf16 Wk,Wv,Wo -> 6000768
constexpr size_t WS_TMPB  = 6000768;    // bf16 [8][2048][256] -> 8097920
constexpr size_t WS_QB    = 8097920;    // bf16 [8][2048][256] -> 10195072
constexpr size_t WS_PART  = 10195072;   // f32 [8][32][256] pooling partials -> 10260608
constexpr size_t WS_MPART = 10260608;   // f32 [8][32] mask partials -> 10260864

static __device__ __forceinline__ ushort f2bf(float f) {
  uint u = __float_as_uint(f);
  return (ushort)((u + 0x7FFFu + ((u >> 16) & 1u)) >> 16);
}
static __device__ __forceinline__ float bf2f(ushort u) {
  return __uint_as_float((uint)u << 16);
}
static __device__ __forceinline__ uint pack2bf(float a, float b) {
  return (uint)f2bf(a) | ((uint)f2bf(b) << 16);
}
// truncating bf16 pack of two floats in one v_perm_b32
static __device__ __forceinline__ uint packtrunc(float lo, float hi) {
  return __builtin_amdgcn_perm(__float_as_uint(hi), __float_as_uint(lo), 0x07060302u);
}

// --- K1: merged — pool partials + q->bf16 | x->x^T bf16 | W->bf16 -----------
__global__ void k_poolprep(const float* __restrict__ q, const float* __restrict__ mask,
                           float* __restrict__ part, float* __restrict__ mpart,
                           ushort* __restrict__ qb,
                           const float* __restrict__ x, const float* __restrict__ Wk,
                           const float* __restrict__ Wv, const float* __restrict__ Wo,
                           ushort* __restrict__ xt, ushort* __restrict__ wb) {
  int bid = blockIdx.x;
  int tid = threadIdx.x;
  __shared__ float shbuf[64 * 65];
  if (bid < 256) {
    int b  = bid >> 5;
    int lc = bid & 31;
    int l0 = lc * 64;
    const float scale = 0.17677669529663687f * 1.4426950408889634f;  // 32^-.5 * log2e
    float* mloc = shbuf;
    if (tid < 64) mloc[tid] = mask[b * CL + l0 + tid];
    __syncthreads();
    if (tid == 0) {
      float s = 0.f;
      for (int j = 0; j < 64; j++) s += mloc[j];
      mpart[b * 32 + lc] = s;
    }
    float acc = 0.f;
    const float* qp = q + (size_t)(b * CL + l0) * CC + tid;
    ushort* qw = qb + (size_t)(b * CL + l0) * CC + tid;
    for (int j = 0; j < 64; j++) {
      float v = qp[(size_t)j * CC];
      acc += v * mloc[j];
      qw[(size_t)j * CC] = f2bf(v * scale);
    }
    part[((size_t)(b * 32 + lc)) * CC + tid] = acc;
  } else if (bid < 384) {
    int b2 = bid - 256;
    int ref  = b2 >> 6;
    int cblk = (b2 >> 4) & 3;
    int hwblk = b2 & 15;
    float (*t)[65] = (float(*)[65])shbuf;
    int c0 = cblk * 64, hw0 = hwblk * 64;
    const float* src = x + (size_t)ref * CC * CHW;
    int hl = tid & 63, cq = tid >> 6;
    #pragma unroll
    for (int r = 0; r < 16; r++) {
      int cl = cq * 16 + r;
      t[cl][hl] = src[(size_t)(c0 + cl) * CHW + hw0 + hl];
    }
    __syncthreads();
    int cl2 = tid & 63, hq = tid >> 6;
    #pragma unroll
    for (int r = 0; r < 16; r++) {
      int hwl = hq * 16 + r;
      xt[((size_t)(ref * CHW + hw0 + hwl)) * CC + c0 + cl2] = f2bf(t[cl2][hwl]);
    }
  } else {
    int t2 = (bid - 384) * 256 + tid;
    int which = t2 >> 13;
    size_t off = ((size_t)(t2 & 8191)) * 8;
    const float* src = (which == 0) ? Wk : (which == 1) ? Wv : Wo;
    float4 a = *(const float4*)(src + off);
    float4 b = *(const float4*)(src + off + 4);
    uint4 r;
    r.x = pack2bf(a.x, a.y); r.y = pack2bf(a.z, a.w);
    r.z = pack2bf(b.x, b.y); r.w = pack2bf(b.z, b.w);
    *(uint4*)(wb + (size_t)which * 65536 + off) = r;
  }
}

// -- K2: fused qcond + modulated/demodulated weights -> bf16 ------------------
// Each block recomputes q_cond for its batch (cheap: 65K MACs, Wq L2-hot),
// eliminating the separate 8-block k_qcond launch + its dependency stall.
__global__ void k_wprep(const float* __restrict__ part, const float* __restrict__ mpart,
                        const float* __restrict__ Wq, const float* __restrict__ bq,
                        const float* __restrict__ Wmod, ushort* __restrict__ wmodb) {
  int b  = blockIdx.x >> 4;
  int og = blockIdx.x & 15;
  int tid = threadIdx.x;
  __shared__ float qm[CC];
  __shared__ float qcond_s[CC];
  __shared__ float msh;

  // reduce pooling partials for this batch
  float s = 0.f;
  const float* pp = part + (size_t)b * 32 * CC + tid;
  #pragma unroll
  for (int lc = 0; lc < 32; lc++) s += pp[(size_t)lc * CC];
  if (tid < 32) {
    float m = mpart[b * 32 + tid];
    #pragma unroll
    for (int k = 1; k < 32; k <<= 1) m += __shfl_xor(m, k, 32);
    if (tid == 0) msh = m;
  }
  __syncthreads();
  qm[tid] = s * (1.f / (msh + 1e-6f));
  __syncthreads();
  // q_cond[b][tid] = bq + Wq row . qm
  float qc = bq[tid];
  const float* wrow = Wq + (size_t)tid * CC;
  for (int i = 0; i < CC; i++) qc += wrow[i] * qm[i];
  qcond_s[tid] = qc;
  __syncthreads();

  int ol = tid >> 4, seg = tid & 15;
  int o = og * 16 + ol;
  const float* wr = Wmod + (size_t)o * CC + seg * 16;
  float m[16];
  float ss = 0.f;
  #pragma unroll
  for (int j = 0; j < 16; j++) {
    float v = wr[j] * (qcond_s[seg * 16 + j] + 1.f);
    m[j] = v;
    ss += v * v;
  }
  #pragma unroll
  for (int k = 1; k < 16; k <<= 1) ss += __shfl_xor(ss, k, 16);
  float d = rsqrtf(ss + 1e-8f);
  uint u[8];
  #pragma unroll
  for (int j = 0; j < 8; j++) u[j] = pack2bf(m[2 * j] * d, m[2 * j + 1] * d);
  ushort* dst = wmodb + ((size_t)(b * CC + o)) * CC + seg * 16;
  *(uint4*)(dst)     = make_uint4(u[0], u[1], u[2], u[3]);
  *(uint4*)(dst + 8) = make_uint4(u[4], u[5], u[6], u[7]);
}

// --- K3: modulated 1x1 conv via MFMA, 2 ot x 2 hwt per wave -> qt bf16 ------
__launch_bounds__(256)
__global__ void k_mod_mfma(const ushort* __restrict__ wmodb, const ushort* __restrict__ xt,
                           ushort* __restrict__ qtb) {
  int tid = threadIdx.x;
  int wid = tid >> 6, lane = tid & 63;
  int widx = blockIdx.x * 4 + wid;     // 2048 waves
  int b   = widx >> 8;                 // 8
  int og  = (widx >> 5) & 7;           // 8 o-pairs
  int hg  = widx & 31;                 // 32 hw-pairs
  int col = lane & 15, g = lane >> 4;
  int O0 = og * 32, HW0 = hg * 32;
  const ushort* ap0 = wmodb + ((size_t)(b * CC + O0 + col)) * CC + g * 8;
  const ushort* ap1 = ap0 + (size_t)16 * CC;
  const ushort* bp0 = xt + ((size_t)((b & 1) * CHW + HW0 + col)) * CC + g * 8;
  const ushort* bp1 = bp0 + (size_t)16 * CC;
  f32x4 acc[2][2];
  #pragma unroll
  for (int X = 0; X < 2; X++)
    #pragma unroll
    for (int Y = 0; Y < 2; Y++)
      acc[X][Y] = (f32x4){0.f, 0.f, 0.f, 0.f};
  #pragma unroll
  for (int ks = 0; ks < 8; ks++) {
    short8 af0 = *(const short8*)(ap0 + ks * 32);
    short8 af1 = *(const short8*)(ap1 + ks * 32);
    short8 bf0 = *(const short8*)(bp0 + ks * 32);
    short8 bf1 = *(const short8*)(bp1 + ks * 32);
    acc[0][0] = __builtin_amdgcn_mfma_f32_16x16x32_bf16(af0, bf0, acc[0][0], 0, 0, 0);
    acc[0][1] = __builtin_amdgcn_mfma_f32_16x16x32_bf16(af0, bf1, acc[0][1], 0, 0, 0);
    acc[1][0] = __builtin_amdgcn_mfma_f32_16x16x32_bf16(af1, bf0, acc[1][0], 0, 0, 0);
    acc[1][1] = __builtin_amdgcn_mfma_f32_16x16x32_bf16(af1, bf1, acc[1][1], 0, 0, 0);
  }
  #pragma unroll
  for (int X = 0; X < 2; X++)
    #pragma unroll
    for (int Y = 0; Y < 2; Y++) {
      uint2 st;
      st.x = pack2bf(acc[X][Y][0], acc[X][Y][1]);
      st.y = pack2bf(acc[X][Y][2], acc[X][Y][3]);
      *(uint2*)(qtb + ((size_t)(b * CHW + HW0 + Y * 16 + col)) * CC + O0 + X * 16 + g * 4) = st;
    }
}

// -- K4: dwconv3x3 + LN + GELU + offset + tanh + ref -> pos -> grid sample ---
__global__ void k_off_sample(const ushort* __restrict__ qtb, const float* __restrict__ dww,
                             const float* __restrict__ dwb, const float* __restrict__ lnw,
                             const float* __restrict__ lnb, const float* __restrict__ offw,
                             const ushort* __restrict__ xt,
                             float* __restrict__ out_pos, float* __restrict__ out_ref,
                             ushort* __restrict__ xst) {
  int bg   = blockIdx.x >> 7;
  int pblk = blockIdx.x & 127;
  int tid  = threadIdx.x;
  int c = tid & 31, pp = tid >> 5;
  int p0 = pblk * 8;
  int yy = p0 >> 5;
  int xx = (p0 & 31) + pp;
  int p  = p0 + pp;
  const ushort* src = qtb + ((size_t)(bg >> 3) * CHW) * CC + (bg & 7) * CGC + c;
  float acc = dwb[c];
  #pragma unroll
  for (int ky = 0; ky < 3; ky++) {
    int yr = yy + ky - 1;
    if (yr < 0 || yr > 31) continue;
    #pragma unroll
    for (int kx = 0; kx < 3; kx++) {
      int xc = xx + kx - 1;
      if (xc < 0 || xc > 31) continue;
      acc += dww[c * 9 + ky * 3 + kx] * bf2f(src[(size_t)(yr * 32 + xc) * CC]);
    }
  }
  float s1 = acc, s2 = acc * acc;
  #pragma unroll
  for (int m = 1; m < 32; m <<= 1) { s1 += __shfl_xor(s1, m, 32); s2 += __shfl_xor(s2, m, 32); }
  float mu  = s1 * (1.f / 32.f);
  float var = s2 * (1.f / 32.f) - mu * mu;
  float tn  = (acc - mu) * rsqrtf(var + 1e-5f) * lnw[c] + lnb[c];
  float g   = 0.5f * tn * (1.f + erff(tn * 0.70710678118654752f));
  float sy = offw[c] * g, sx = offw[32 + c] * g;
  #pragma unroll
  for (int m = 1; m < 32; m <<= 1) { sy += __shfl_xor(sy, m, 32); sx += __shfl_xor(sx, m, 32); }

  float mine  = tanhf((c & 1) ? sx : sy);
  float other = __shfl_xor(mine, 1, 32);
  float ty = (c & 1) ? other : mine;
  float tx = (c & 1) ? mine : other;

  float refy = (0.5f + (float)yy) * (2.f / 31.f) - 1.f;
  float refx = (0.5f + (float)xx) * (2.f / 31.f) - 1.f;
  float py = ty * (2.f / 31.f) + refy;
  float px = tx * (2.f / 31.f) + refx;
  if (c < 2) {
    int oidx = bg * 2048 + p * 2 + c;
    out_pos[oidx] = (c == 0) ? py : px;
    out_ref[oidx] = (c == 0) ? refy : refx;
  }

  float gx = (px + 1.f) * 15.5f;
  float gy = (py + 1.f) * 15.5f;
  float x0f = floorf(gx), y0f = floorf(gy);
  float wx = gx - x0f, wy = gy - y0f;
  int ix0 = (int)x0f, iy0 = (int)y0f;
  const ushort* img = xt + (size_t)(((bg >> 3) & 1)) * CHW * CC + (bg & 7) * CGC + c;
  float sacc = 0.f;
  #pragma unroll
  for (int dy = 0; dy < 2; dy++) {
    int iy = iy0 + dy;
    if (iy < 0 || iy > 31) continue;
    float wyv = dy ? wy : 1.f - wy;
    #pragma unroll
    for (int dx = 0; dx < 2; dx++) {
      int ix = ix0 + dx;
      if (ix < 0 || ix > 31) continue;
      float wxv = dx ? wx : 1.f - wx;
      sacc += wyv * wxv * bf2f(img[(size_t)(iy * 32 + ix) * CC]);
    }
  }
  xst[((size_t)((bg >> 3) * CNS) + p) * CC + (bg & 7) * CGC + c] = f2bf(sacc);
}

// -------- K6: fused K/V projection via MFMA, 2 nt x 2 ot per wave -----------
__launch_bounds__(256)
__global__ void k_kv_mfma(const ushort* __restrict__ xst, const ushort* __restrict__ wkb,
                          const ushort* __restrict__ wvb, const float* __restrict__ bk,
                          const float* __restrict__ bv, ushort* __restrict__ kb,
                          ushort* __restrict__ vb) {
  int tid = threadIdx.x;
  int wid = tid >> 6, lane = tid & 63;
  int widx = blockIdx.x * 4 + wid;       // 2048 waves
  int b   = widx >> 8;                   // 8
  int ntg = (widx >> 3) & 31;            // 32 nt-pairs
  int otg = widx & 7;                    // 8 ot-pairs
  int col = lane & 15, g = lane >> 4;
  int N0 = ntg * 32, O0 = otg * 32;

  const ushort* xs0 = xst + ((size_t)(b * CNS + N0 + col)) * CC + g * 8;
  const ushort* xs1 = xs0 + (size_t)16 * CC;
  const ushort* wk0 = wkb + (size_t)(O0 + col) * CC + g * 8;
  const ushort* wk1 = wk0 + (size_t)16 * CC;
  const ushort* wv0 = wvb + (size_t)(O0 + col) * CC + g * 8;
  const ushort* wv1 = wv0 + (size_t)16 * CC;

  f32x4 ka[2][2], va[2][2];
  #pragma unroll
  for (int Y = 0; Y < 2; Y++) {
    float bvv = bv[O0 + Y * 16 + col];
    #pragma unroll
    for (int r = 0; r < 4; r++) {
      float bkv = bk[O0 + Y * 16 + g * 4 + r];
      ka[0][Y][r] = bkv; ka[1][Y][r] = bkv;
      va[0][Y][r] = bvv; va[1][Y][r] = bvv;
    }
  }

  #pragma unroll
  for (int ks = 0; ks < 8; ks++) {
    short8 xf0 = *(const short8*)(xs0 + ks * 32);
    short8 xf1 = *(const short8*)(xs1 + ks * 32);
    short8 kf0 = *(const short8*)(wk0 + ks * 32);
    short8 kf1 = *(const short8*)(wk1 + ks * 32);
    short8 vf0 = *(const short8*)(wv0 + ks * 32);
    short8 vf1 = *(const short8*)(wv1 + ks * 32);
    ka[0][0] = __builtin_amdgcn_mfma_f32_16x16x32_bf16(kf0, xf0, ka[0][0], 0, 0, 0);
    ka[0][1] = __builtin_amdgcn_mfma_f32_16x16x32_bf16(kf1, xf0, ka[0][1], 0, 0, 0);
    ka[1][0] = __builtin_amdgcn_mfma_f32_16x16x32_bf16(kf0, xf1, ka[1][0], 0, 0, 0);
    ka[1][1] = __builtin_amdgcn_mfma_f32_16x16x32_bf16(kf1, xf1, ka[1][1], 0, 0, 0);
    va[0][0] = __builtin_amdgcn_mfma_f32_16x16x32_bf16(xf0, vf0, va[0][0], 0, 0, 0);
    va[0][1] = __builtin_amdgcn_mfma_f32_16x16x32_bf16(xf0, vf1, va[0][1], 0, 0, 0);
    va[1][0] = __builtin_amdgcn_mfma_f32_16x16x32_bf16(xf1, vf0, va[1][0], 0, 0, 0);
    va[1][1] = __builtin_amdgcn_mfma_f32_16x16x32_bf16(xf1, vf1, va[1][1], 0, 0, 0);
  }

  #pragma unroll
  for (int X = 0; X < 2; X++)
    #pragma unroll
    for (int Y = 0; Y < 2; Y++) {
      int Oy = O0 + Y * 16, Nx = N0 + X * 16;
      {
        int hh = Oy >> 5;
        int c0 = (Oy & 31) + g * 4;
        uint2 w;
        w.x = pack2bf(ka[X][Y][0], ka[X][Y][1]);
        w.y = pack2bf(ka[X][Y][2], ka[X][Y][3]);
        *(uint2*)(kb + ((size_t)((b * 8 + hh) * CNS + Nx + col)) * CHC + c0) = w;
      }
      {
        int o = Oy + col;
        int hh = o >> 5;
        uint2 w;
        w.x = pack2bf(va[X][Y][0], va[X][Y][1]);
        w.y = pack2bf(va[X][Y][2], va[X][Y][3]);
        *(uint2*)(vb + ((size_t)((b * 8 + hh) * CHC + (o & 31))) * CNS + Nx + g * 4) = w;
      }
    }
}

// -------- K7: MFMA flash attention, 2 chunks per barrier (r13 best) ----------
__launch_bounds__(512, 4)
__global__ void k_attn_mfma(const ushort* __restrict__ qb, const ushort* __restrict__ kb,
                            const ushort* __restrict__ vb, ushort* __restrict__ tmpb) {
  int bh = blockIdx.x >> 3;          // 64
  int mb = blockIdx.x & 7;           // 8 m-blocks of 256 rows
  int b = bh >> 3, h = bh & 7;
  int tid = threadIdx.x;
  int wid = tid >> 6, lane = tid & 63;
  int col = lane & 15, g = lane >> 4;
  int mA = mb * 256 + wid * 32 + col;    // tile A rows; tile B = +16

  __shared__ ushort Kst[2][2][64 * 40];  // [buf][slot] 80B rows
  __shared__ ushort Vst[2][2][32 * 72];  // [buf][slot] 144B rows
  __shared__ ushort plds[8][2048];       // dual 2KB P buffers per wave

  char* pwA = (char*)&plds[wid][0];
  char* pwB = (char*)&plds[wid][1024];
  int swz = (col & 7) << 4;
  int wb0 = col * 128 + g * 8;
  int rb0 = (col * 128 + g * 16) ^ swz;
  int rb1 = (col * 128 + 64 + g * 16) ^ swz;

  const ushort* qpA = qb + ((size_t)(b * CL + mA)) * CC + h * CHC + g * 8;
  short8 qfA = *(const short8*)qpA;
  short8 qfB = *(const short8*)(qpA + 16 * CC);

  const ushort* kglob = kb + (size_t)bh * 32768 + tid * 4;            // [n][c]
  const ushort* vglob = vb + (size_t)bh * 32768 + (tid >> 4) * 1024 + (tid & 15) * 4;  // [c][n]
  int kdst = (tid >> 3) * 40 + (tid & 7) * 4;
  int vdst = (tid >> 4) * 72 + (tid & 15) * 4;

  f32x4 oA0 = {0.f,0.f,0.f,0.f}, oA1 = {0.f,0.f,0.f,0.f};
  f32x4 oB0 = {0.f,0.f,0.f,0.f}, oB1 = {0.f,0.f,0.f,0.f};
  float lA = 0.f, lB = 0.f;

  {
    uint2 k0 = *(const uint2*)(kglob);
    uint2 k1 = *(const uint2*)(kglob + 2048);
    uint2 v0 = *(const uint2*)(vglob);
    uint2 v1 = *(const uint2*)(vglob + 64);
    *(uint2*)&Kst[0][0][kdst] = k0;
    *(uint2*)&Kst[0][1][kdst] = k1;
    *(uint2*)&Vst[0][0][vdst] = v0;
    *(uint2*)&Vst[0][1][vdst] = v1;
  }
  __syncthreads();

  int cur = 0;
  for (int it = 0; it < 8; it++) {
    uint2 kx0, kx1, vx0, vx1;
    if (it < 7) {
      int cb = (it + 1) * 2;
      kx0 = *(const uint2*)(kglob + (size_t)cb * 2048);
      kx1 = *(const uint2*)(kglob + (size_t)(cb + 1) * 2048);
      vx0 = *(const uint2*)(vglob + (size_t)cb * 64);
      vx1 = *(const uint2*)(vglob + (size_t)(cb + 1) * 64);
    }

    #pragma unroll
    for (int s = 0; s < 2; s++) {
      const ushort* Kc = &Kst[cur][s][0];
      const ushort* Vc = &Vst[cur][s][0];
      short8 kf0 = *(const short8*)(Kc + ( 0 + col) * 40 + g * 8);
      short8 kf1 = *(const short8*)(Kc + (16 + col) * 40 + g * 8);
      short8 kf2 = *(const short8*)(Kc + (32 + col) * 40 + g * 8);
      short8 kf3 = *(const short8*)(Kc + (48 + col) * 40 + g * 8);
      short8 vf00 = *(const short8*)(Vc + (col     ) * 72 +  0 + g * 8);
      short8 vf01 = *(const short8*)(Vc + (col     ) * 72 + 32 + g * 8);
      short8 vf10 = *(const short8*)(Vc + (col + 16) * 72 +  0 + g * 8);
      short8 vf11 = *(const short8*)(Vc + (col + 16) * 72 + 32 + g * 8);

      f32x4 zero = {0.f,0.f,0.f,0.f};
      f32x4 sA0 = __builtin_amdgcn_mfma_f32_16x16x32_bf16(kf0, qfA, zero, 0, 0, 0);
      f32x4 sA1 = __builtin_amdgcn_mfma_f32_16x16x32_bf16(kf1, qfA, zero, 0, 0, 0);
      f32x4 sA2 = __builtin_amdgcn_mfma_f32_16x16x32_bf16(kf2, qfA, zero, 0, 0, 0);
      f32x4 sA3 = __builtin_amdgcn_mfma_f32_16x16x32_bf16(kf3, qfA, zero, 0, 0, 0);
      f32x4 sB0 = __builtin_amdgcn_mfma_f32_16x16x32_bf16(kf0, qfB, zero, 0, 0, 0);
      f32x4 sB1 = __builtin_amdgcn_mfma_f32_16x16x32_bf16(kf1, qfB, zero, 0, 0, 0);
      f32x4 sB2 = __builtin_amdgcn_mfma_f32_16x16x32_bf16(kf2, qfB, zero, 0, 0, 0);
      f32x4 sB3 = __builtin_amdgcn_mfma_f32_16x16x32_bf16(kf3, qfB, zero, 0, 0, 0);

      {
        float ps = 0.f;
        #pragma unroll
        for (int f = 0; f < 4; f++) {
          f32x4 sv = (f == 0) ? sA0 : (f == 1) ? sA1 : (f == 2) ? sA2 : sA3;
          float p0 = __builtin_amdgcn_exp2f(sv[0]);
          float p1 = __builtin_amdgcn_exp2f(sv[1]);
          float p2 = __builtin_amdgcn_exp2f(sv[2]);
          float p3 = __builtin_amdgcn_exp2f(sv[3]);
          ps += (p0 + p1) + (p2 + p3);
          *(uint2*)(pwA + ((wb0 + f * 32) ^ swz)) = make_uint2(packtrunc(p0, p1), packtrunc(p2, p3));
        }
        lA += ps;
      }
      {
        float ps = 0.f;
        #pragma unroll
        for (int f = 0; f < 4; f++) {
          f32x4 sv = (f == 0) ? sB0 : (f == 1) ? sB1 : (f == 2) ? sB2 : sB3;
          float p0 = __builtin_amdgcn_exp2f(sv[0]);
          float p1 = __builtin_amdgcn_exp2f(sv[1]);
          float p2 = __builtin_amdgcn_exp2f(sv[2]);
          float p3 = __builtin_amdgcn_exp2f(sv[3]);
          ps += (p0 + p1) + (p2 + p3);
          *(uint2*)(pwB + ((wb0 + f * 32) ^ swz)) = make_uint2(packtrunc(p0, p1), packtrunc(p2, p3));
        }
        lB += ps;
      }

      short8 pfA0 = *(const short8*)(pwA + rb0);
      short8 pfA1 = *(const short8*)(pwA + rb1);
      short8 pfB0 = *(const short8*)(pwB + rb0);
      short8 pfB1 = *(const short8*)(pwB + rb1);

      oA0 = __builtin_amdgcn_mfma_f32_16x16x32_bf16(vf00, pfA0, oA0, 0, 0, 0);
      oA0 = __builtin_amdgcn_mfma_f32_16x16x32_bf16(vf01, pfA1, oA0, 0, 0, 0);
      oA1 = __builtin_amdgcn_mfma_f32_16x16x32_bf16(vf10, pfA0, oA1, 0, 0, 0);
      oA1 = __builtin_amdgcn_mfma_f32_16x16x32_bf16(vf11, pfA1, oA1, 0, 0, 0);
      oB0 = __builtin_amdgcn_mfma_f32_16x16x32_bf16(vf00, pfB0, oB0, 0, 0, 0);
      oB0 = __builtin_amdgcn_mfma_f32_16x16x32_bf16(vf01, pfB1, oB0, 0, 0, 0);
      oB1 = __builtin_amdgcn_mfma_f32_16x16x32_bf16(vf10, pfB0, oB1, 0, 0, 0);
      oB1 = __builtin_amdgcn_mfma_f32_16x16x32_bf16(vf11, pfB1, oB1, 0, 0, 0);
    }

    if (it < 7) {
      *(uint2*)&Kst[cur ^ 1][0][kdst] = kx0;
      *(uint2*)&Kst[cur ^ 1][1][kdst] = kx1;
      *(uint2*)&Vst[cur ^ 1][0][vdst] = vx0;
      *(uint2*)&Vst[cur ^ 1][1][vdst] = vx1;
    }
    __syncthreads();
    cur ^= 1;
  }

  lA += __shfl_xor(lA, 16); lA += __shfl_xor(lA, 32);
  lB += __shfl_xor(lB, 16); lB += __shfl_xor(lB, 32);
  float rlA = 1.f / lA, rlB = 1.f / lB;

  ushort* opA = tmpb + ((size_t)(b * CL + mA)) * CC + h * CHC;
  ushort* opB = opA + 16 * CC;
  {
    uint2 w0, w1;
    w0.x = pack2bf(oA0[0] * rlA, oA0[1] * rlA);
    w0.y = pack2bf(oA0[2] * rlA, oA0[3] * rlA);
    w1.x = pack2bf(oA1[0] * rlA, oA1[1] * rlA);
    w1.y = pack2bf(oA1[2] * rlA, oA1[3] * rlA);
    *(uint2*)(opA + g * 4) = w0;
    *(uint2*)(opA + 16 + g * 4) = w1;
  }
  {
    uint2 w0, w1;
    w0.x = pack2bf(oB0[0] * rlB, oB0[1] * rlB);
    w0.y = pack2bf(oB0[2] * rlB, oB0[3] * rlB);
    w1.x = pack2bf(oB1[0] * rlB, oB1[1] * rlB);
    w1.y = pack2bf(oB1[2] * rlB, oB1[3] * rlB);
    *(uint2*)(opB + g * 4) = w0;
    *(uint2*)(opB + 16 + g * 4) = w1;
  }
}

// ------- K8: y = tmp_bf @ Wo_bf^T + bo via MFMA (2 r-tiles x 8 o-tiles) -----
__launch_bounds__(256)
__global__ void k_yproj_mfma(const ushort* __restrict__ tmpb, const ushort* __restrict__ wob,
                             const float* __restrict__ bo, float* __restrict__ y) {
  int tid = threadIdx.x;
  int wid = tid >> 6, lane = tid & 63;
  int widx = blockIdx.x * 4 + wid;      // 1024 waves
  int rt2 = widx >> 1;                  // 512 row-pairs
  int og = widx & 1;                    // 2 o-groups of 128
  int col = lane & 15, g = lane >> 4;
  int R0 = rt2 * 32, O0 = og * 128;

  const ushort* ap0 = tmpb + ((size_t)(R0 + col)) * CC + g * 8;
  const ushort* ap1 = ap0 + (size_t)16 * CC;
  const ushort* bp = wob + (size_t)(O0 + col) * CC + g * 8;

  f32x4 acc[2][8];
  #pragma unroll
  for (int o4 = 0; o4 < 8; o4++) {
    float bb = bo[O0 + o4 * 16 + col];
    #pragma unroll
    for (int r = 0; r < 4; r++) { acc[0][o4][r] = bb; acc[1][o4][r] = bb; }
  }

  #pragma unroll
  for (int ks = 0; ks < 8; ks++) {
    short8 af0 = *(const short8*)(ap0 + ks * 32);
    short8 af1 = *(const short8*)(ap1 + ks * 32);
    #pragma unroll
    for (int o4 = 0; o4 < 8; o4++) {
      short8 bf = *(const short8*)(bp + (size_t)o4 * 16 * CC + ks * 32);
      acc[0][o4] = __builtin_amdgcn_mfma_f32_16x16x32_bf16(af0, bf, acc[0][o4], 0, 0, 0);
      acc[1][o4] = __builtin_amdgcn_mfma_f32_16x16x32_bf16(af1, bf, acc[1][o4], 0, 0, 0);
    }
  }

  #pragma unroll
  for (int rr = 0; rr < 2; rr++)
    #pragma unroll
    for (int o4 = 0; o4 < 8; o4++)
      #pragma unroll
      for (int r = 0; r < 4; r++)
        y[(size_t)(R0 + rr * 16 + g * 4 + r) * CC + O0 + o4 * 16 + col] = acc[rr][o4][r];
}

extern "C" void kernel_launch(void* const* d_in, const int* in_sizes, int n_in,
                              void* d_out, int out_size, void* d_ws, size_t ws_size,
                              hipStream_t stream) {
  const float* x    = (const float*)d_in[0];
  const float* q    = (const float*)d_in[1];
  const float* mask = (const float*)d_in[2];
  const float* Wq   = (const float*)d_in[3];
  const float* bq   = (const float*)d_in[4];
  const float* Wmod = (const float*)d_in[5];
  const float* dw_w = (const float*)d_in[6];
  const float* dw_b = (const float*)d_in[7];
  const float* ln_w = (const float*)d_in[8];
  const float* ln_b = (const float*)d_in[9];
  const float* offw = (const float*)d_in[10];
  const float* Wk   = (const float*)d_in[11];
  const float* bk   = (const float*)d_in[12];
  const float* Wv   = (const float*)d_in[13];
  const float* bv   = (const float*)d_in[14];
  const float* Wo   = (const float*)d_in[15];
  const float* bo   = (const float*)d_in[16];

  float* ws = (float*)d_ws;
  float* out = (float*)d_out;
  float* out_y   = out;
  float* out_pos = out + (size_t)CB * CL * CC;
  float* out_ref = out_pos + (size_t)CBG * CHW * 2;

  ushort* wmodb = (ushort*)(ws + WS_WMOD);
  ushort* xt    = (ushort*)(ws + WS_XT);
  ushort* qtb   = (ushort*)(ws + WS_QT);
  ushort* xst   = (ushort*)(ws + WS_XST);
  ushort* kbuf  = (ushort*)(ws + WS_KB);
  ushort* vbuf  = (ushort*)(ws + WS_VB);
  ushort* wkb   = (ushort*)(ws + WS_WB);
  ushort* wvb   = wkb + 65536;
  ushort* wob   = wkb + 131072;
  ushort* tmpb  = (ushort*)(ws + WS_TMPB);
  ushort* qbuf  = (ushort*)(ws + WS_QB);
  float*  part  = ws + WS_PART;
  float*  mpart = ws + WS_MPART;

  k_poolprep<<<480, 256, 0, stream>>>(q, mask, part, mpart, qbuf, x, Wk, Wv, Wo, xt, wkb);
  k_wprep<<<128, 256, 0, stream>>>(part, mpart, Wq, bq, Wmod, wmodb);
  k_mod_mfma<<<512, 256, 0, stream>>>(wmodb, xt, qtb);
  k_off_sample<<<8192, 256, 0, stream>>>(qtb, dw_w, dw_b, ln_w, ln_b, offw, xt,
                                         out_pos, out_ref, xst);
  k_kv_mfma<<<512, 256, 0, stream>>>(xst, wkb, wvb, bk, bv, kbuf, vbuf);
  k_attn_mfma<<<512, 512, 0, stream>>>(qbuf, kbuf, vbuf, tmpb);
  k_yproj_mfma<<<256, 256, 0, stream>>>(tmpb, wob, bo, out_y);
}